// Round 1
// 1140.351 us; speedup vs baseline: 1.0704x; 1.0704x over previous
//
#include <hip/hip_runtime.h>
#include <hip/hip_bf16.h>

typedef __hip_bfloat16 bf16;
typedef float v4f __attribute__((ext_vector_type(4)));
typedef short v8s __attribute__((ext_vector_type(8)));

#define KSEL 307

__device__ static inline void async16(bf16* lds, const bf16* g) {
    __builtin_amdgcn_global_load_lds(
        (const __attribute__((address_space(1))) void*)g,
        (__attribute__((address_space(3))) void*)lds, 16, 0, 0);
}

__device__ static inline unsigned short f2bu(float f) {
    __hip_bfloat16 h = __float2bfloat16(f);
    return *reinterpret_cast<unsigned short*>(&h);
}

__device__ static inline unsigned pk2(float a, float b) {
    __hip_bfloat162 h = __float22bfloat162_rn(make_float2(a, b));
    return *reinterpret_cast<unsigned*>(&h);
}

// tanh-approx gelu via hardware exp: ~8 VALU ops vs ~35 for erff.
// max abs err ~1e-3, fine vs 0.105 threshold.
__device__ static inline float gelu_f(float v) {
    float c = v * fmaf(v * v, 0.0356774081f, 0.7978845608f);
    return v / (1.0f + __expf(-2.0f * c));
}

// ---------------- fp32 -> bf16 convert, 7 segments in one launch ----------------
struct F2BP { const float* src[7]; bf16* dst[7]; int n4[7]; };

__global__ void __launch_bounds__(256) f2b_multi(F2BP p) {
    int s = blockIdx.y;
    const float* __restrict__ in = p.src[s];
    bf16* __restrict__ out = p.dst[s];
    int n4 = p.n4[s];
    for (int i = blockIdx.x * 256 + threadIdx.x; i < n4; i += gridDim.x * 256) {
        float4 v = ((const float4*)in)[i];
        ushort4 u = make_ushort4(f2bu(v.x), f2bu(v.y), f2bu(v.z), f2bu(v.w));
        ((ushort4*)out)[i] = u;
    }
}

// ---------------- LayerNorm (row of 1024) ----------------
__global__ void __launch_bounds__(256) ln_kernel(const float* __restrict__ x,
                                                 const float* __restrict__ g,
                                                 const float* __restrict__ be,
                                                 bf16* __restrict__ out) {
    int row = blockIdx.x;
    int tid = threadIdx.x;
    const float* xr = x + row * 1024;
    float4 v = ((const float4*)xr)[tid];
    float s = v.x + v.y + v.z + v.w;
    float s2 = v.x*v.x + v.y*v.y + v.z*v.z + v.w*v.w;
    for (int off = 32; off > 0; off >>= 1) {
        s  += __shfl_down(s, off);
        s2 += __shfl_down(s2, off);
    }
    __shared__ float sh[4], sh2[4];
    int w = tid >> 6;
    if ((tid & 63) == 0) { sh[w] = s; sh2[w] = s2; }
    __syncthreads();
    float mean = (sh[0]+sh[1]+sh[2]+sh[3]) * (1.0f / 1024.f);
    float ms   = (sh2[0]+sh2[1]+sh2[2]+sh2[3]) * (1.0f / 1024.f);
    float var  = ms - mean*mean;
    float rs   = rsqrtf(var + 1e-5f);
    float4 gg = ((const float4*)g)[tid];
    float4 bb = ((const float4*)be)[tid];
    ushort4 o = make_ushort4(
        f2bu((v.x-mean)*rs*gg.x + bb.x),
        f2bu((v.y-mean)*rs*gg.y + bb.y),
        f2bu((v.z-mean)*rs*gg.z + bb.z),
        f2bu((v.w-mean)*rs*gg.w + bb.w));
    ((ushort4*)out)[row * 256 + tid] = o;
}

// ---------------- top-k threshold + masked softmax (in place, fp32 row of 1024) ---
__global__ void __launch_bounds__(256) topk_softmax(float* __restrict__ sc) {
    float* p = sc + (long long)blockIdx.x * 1024;
    int tid = threadIdx.x;
    int w = tid >> 6;
    float4 v4 = ((const float4*)p)[tid];
    float v[4] = {v4.x, v4.y, v4.z, v4.w};
    unsigned key[4];
#pragma unroll
    for (int j = 0; j < 4; ++j) {
        unsigned u = __float_as_uint(v[j]);
        key[j] = (u & 0x80000000u) ? ~u : (u | 0x80000000u);
    }
    __shared__ int hist[4][256];
    __shared__ int cnt[256];
    __shared__ int suf[256];
    __shared__ int sh_b, sh_above;
    unsigned prefix = 0;
    int need = KSEL;
    for (int pass = 0; pass < 2; ++pass) {
        int shift = 24 - 8 * pass;
        hist[0][tid] = 0; hist[1][tid] = 0; hist[2][tid] = 0; hist[3][tid] = 0;
        __syncthreads();
#pragma unroll
        for (int j = 0; j < 4; ++j) {
            bool cand = (pass == 0) || ((key[j] >> 24) == prefix);
            if (cand) atomicAdd(&hist[w][(key[j] >> shift) & 255], 1);
        }
        __syncthreads();
        cnt[tid] = hist[0][tid] + hist[1][tid] + hist[2][tid] + hist[3][tid];
        __syncthreads();
        if (tid < 64) {
            int h0 = cnt[tid*4], h1 = cnt[tid*4+1], h2 = cnt[tid*4+2], h3 = cnt[tid*4+3];
            int gs = h0 + h1 + h2 + h3;
            int sfx = gs;
            for (int off = 1; off < 64; off <<= 1) {
                int o = __shfl_down(sfx, off);
                if (tid + off < 64) sfx += o;
            }
            int above = sfx - gs;
            suf[tid*4+0] = above + gs;
            suf[tid*4+1] = above + h1 + h2 + h3;
            suf[tid*4+2] = above + h2 + h3;
            suf[tid*4+3] = above + h3;
        }
        __syncthreads();
        if (suf[tid] >= need && (tid == 255 || suf[tid+1] < need)) {
            sh_b = tid;
            sh_above = (tid == 255) ? 0 : suf[tid+1];
        }
        __syncthreads();
        prefix = (prefix << 8) | (unsigned)sh_b;
        need -= sh_above;
    }
    float mx = fmaxf(fmaxf(v[0], v[1]), fmaxf(v[2], v[3]));
    for (int off = 32; off > 0; off >>= 1) mx = fmaxf(mx, __shfl_down(mx, off));
    __shared__ float shm[4], shs[4];
    if ((tid & 63) == 0) shm[w] = mx;
    __syncthreads();
    mx = fmaxf(fmaxf(shm[0], shm[1]), fmaxf(shm[2], shm[3]));
    float e[4];
    float sum = 0.f;
#pragma unroll
    for (int j = 0; j < 4; ++j) {
        bool sel = (key[j] >> 16) >= prefix;
        e[j] = sel ? __expf(v[j] - mx) : 0.f;
        sum += e[j];
    }
    for (int off = 32; off > 0; off >>= 1) sum += __shfl_down(sum, off);
    if ((tid & 63) == 0) shs[w] = sum;
    __syncthreads();
    float inv = 1.0f / (shs[0] + shs[1] + shs[2] + shs[3]);
    float4 o;
    o.x = e[0]*inv; o.y = e[1]*inv; o.z = e[2]*inv; o.w = e[3]*inv;
    ((float4*)p)[tid] = o;
}

// ---------------- templated BT GEMM (128x128 tile): used for QKV/Wo/W2/QK^T ----
template<int K, int LDA, int LDB, int LDC, int N, int BMODE, int ACT, int BM>
__global__ void __launch_bounds__(256) gemm_t(const bf16* __restrict__ A,
                                              const bf16* __restrict__ B,
                                              float* __restrict__ Cf,
                                              bf16* __restrict__ Cb,
                                              const float* __restrict__ bias,
                                              const float* __restrict__ resid,
                                              float scale) {
    __shared__ __align__(16) bf16 As[128 * 32];
    __shared__ __align__(16) bf16 Bs[128 * 32];
    int offA = 0, offB = 0, offC = 0;
    if (BM == 1) {
        int z = blockIdx.z;
        int b = z >> 4, h = z & 15;
        offA = b * 1048576 + h * 64;
        offB = offA;
        offC = z * 1048576;
    }
    const int tid = threadIdx.x;
    const int w = tid >> 6, lane = tid & 63;
    const int tm = blockIdx.y * 128, tn = blockIdx.x * 128;
    const int q = lane >> 4, m16 = lane & 15;
    const int r0 = (w >> 1) * 64, c0 = (w & 1) * 64;
    const int srow = lane >> 2, scol = (lane & 3) * 8;

    v4f acc[4][4];
#pragma unroll
    for (int i = 0; i < 4; ++i)
#pragma unroll
        for (int j = 0; j < 4; ++j) acc[i][j] = (v4f){0.f, 0.f, 0.f, 0.f};

    const bf16* Ab = A + offA + (tm + w * 16 + srow) * LDA + scol;
    const bf16* Bb = B + offB + (tn + w * 16 + srow) * LDB + scol;
    bf16* Asw = &As[(w * 16) * 32];
    bf16* Bsw = &Bs[(w * 16) * 32];

#pragma unroll 1
    for (int k0 = 0; k0 < K; k0 += 32) {
        async16(Asw,           Ab + k0);
        async16(Asw + 64 * 32, Ab + 64 * LDA + k0);
        async16(Bsw,           Bb + k0);
        async16(Bsw + 64 * 32, Bb + 64 * LDB + k0);
        __syncthreads();
        v8s af[4], bfr[4];
#pragma unroll
        for (int i = 0; i < 4; ++i)
            af[i] = *(const v8s*)&As[(r0 + 16 * i + m16) * 32 + q * 8];
#pragma unroll
        for (int j = 0; j < 4; ++j)
            bfr[j] = *(const v8s*)&Bs[(c0 + 16 * j + m16) * 32 + q * 8];
#pragma unroll
        for (int i = 0; i < 4; ++i)
#pragma unroll
            for (int j = 0; j < 4; ++j)
                acc[i][j] = __builtin_amdgcn_mfma_f32_16x16x32_bf16(af[i], bfr[j], acc[i][j], 0, 0, 0);
        __syncthreads();
    }

    float bc[4];
#pragma unroll
    for (int j = 0; j < 4; ++j)
        bc[j] = (BMODE == 1) ? bias[tn + c0 + 16 * j + m16] : 0.f;

#pragma unroll
    for (int i = 0; i < 4; ++i) {
#pragma unroll
        for (int r = 0; r < 4; ++r) {
            int row = tm + r0 + 16 * i + q * 4 + r;
            float br = (BMODE == 2) ? bias[row] : 0.f;
            int rowbase = offC + row * LDC + tn + c0 + m16;
#pragma unroll
            for (int j = 0; j < 4; ++j) {
                float v = acc[i][j][r] * scale + bc[j] + br;
                if (ACT) v = gelu_f(v);
                int idx = rowbase + 16 * j;
                if (resid) v += resid[idx];
                if (Cf) Cf[idx] = v;
                if (Cb) Cb[idx] = __float2bfloat16(v);
            }
        }
    }
}

// ---------------- 256x256 deep-pipelined GEMM (W1, Wm): 8 waves, BK=32,
// 4-deep LDS ring, counted vmcnt(4), per-phase barrier+setprio interleave.
// C[m,n] = gelu(sum_k A[m,k]*B[n,k] + bias[n]), bf16 out.
template<int K, int LDA, int LDB, int LDC>
__global__ void __launch_bounds__(512, 2) gemm256(const bf16* __restrict__ A,
                                                  const bf16* __restrict__ B,
                                                  bf16* __restrict__ C,
                                                  const float* __restrict__ bias) {
    // ring of 4 K-tiles: 4 * (256x32 A + 256x32 B) bf16 = 128 KiB
    __shared__ __align__(16) bf16 As[4][256 * 32];
    __shared__ __align__(16) bf16 Bs[4][256 * 32];

    constexpr int nt = K / 32;
    static_assert(nt >= 4 && (nt % 4) == 0, "K must be multiple of 128");

    const int tid = threadIdx.x;
    const int w = tid >> 6, lane = tid & 63;
    const int wm = w >> 2, wn = w & 3;          // 2 x 4 wave grid
    const int q = lane >> 4, m16 = lane & 15;

    // XCD-chunked remap of the 16x16 grid: XCD x owns a 4-row x 8-col tile region
    // (256 blocks, 256 CUs, 1 block/CU; HW round-robins dispatch index over 8 XCDs).
    int bid = blockIdx.y * 16 + blockIdx.x;
    int xcd = bid & 7, inner = bid >> 3;
    int by = (xcd & 3) * 4 + (inner & 3);
    int bx = (xcd >> 2) * 8 + (inner >> 2);
    const int tm = by * 256, tn = bx * 256;

    // staging: wave w owns rows [w*32, w*32+32) of each 256-row tile; two
    // global_load_lds(16B) per tile-half; LDS dest is wave-uniform base + lane*16.
    const int srow = lane >> 2;            // 0..15
    const int scol = (lane & 3) * 8;       // 0,8,16,24 (bf16 elems = 16B chunks)
    const bf16* Ag = A + (tm + w * 32 + srow) * LDA + scol;
    const bf16* Bg = B + (tn + w * 32 + srow) * LDB + scol;

    v4f acc[8][4];
#pragma unroll
    for (int i = 0; i < 8; ++i)
#pragma unroll
        for (int j = 0; j < 4; ++j) acc[i][j] = (v4f){0.f, 0.f, 0.f, 0.f};

    // fragment read offsets (elements). BK=32 rows are 64B -> ds_read_b128 of a
    // 16-row fragment group is naturally bank-uniform (8 lanes per 16B slot).
    const int aoff = (wm * 128 + m16) * 32 + q * 8;
    const int boff = (wn * 64 + m16) * 32 + q * 8;

    // ---- prologue: stage K-tiles 0,1 into ring slots 0,1 (8 loads/wave) ----
#pragma unroll
    for (int t = 0; t < 2; ++t) {
        async16(&As[t][(w * 32) * 32],      Ag + t * 32);
        async16(&As[t][(w * 32 + 16) * 32], Ag + 16 * LDA + t * 32);
        async16(&Bs[t][(w * 32) * 32],      Bg + t * 32);
        async16(&Bs[t][(w * 32 + 16) * 32], Bg + 16 * LDB + t * 32);
    }
    asm volatile("s_waitcnt vmcnt(4)" ::: "memory");   // tile 0 landed; tile 1 in flight
    __builtin_amdgcn_s_barrier();
    __builtin_amdgcn_sched_barrier(0);

#pragma unroll 1
    for (int t4 = 0; t4 < nt; t4 += 4) {
#pragma unroll
        for (int tt = 0; tt < 4; ++tt) {
            const int t = t4 + tt;
            const int cur = tt;                 // ring slot being computed
            const int pre = (tt + 2) & 3;       // ring slot being staged (t+2)
            int kt = t + 2; if (kt >= nt) kt = 0;   // clamp: dead staging at tail
            const bf16* Asrc = Ag + kt * 32;
            const bf16* Bsrc = Bg + kt * 32;

            // ---------------- phase A: rows 0..63 of wave tile ----------------
            v8s af[4], bfr[4];
#pragma unroll
            for (int i = 0; i < 4; ++i)
                af[i] = *(const v8s*)&As[cur][aoff + i * 512];
#pragma unroll
            for (int j = 0; j < 4; ++j)
                bfr[j] = *(const v8s*)&Bs[cur][boff + j * 512];
            async16(&As[pre][(w * 32) * 32],      Asrc);
            async16(&As[pre][(w * 32 + 16) * 32], Asrc + 16 * LDA);
            __builtin_amdgcn_s_barrier();
            asm volatile("s_waitcnt lgkmcnt(0)" ::: "memory");
            __builtin_amdgcn_sched_barrier(0);
            __builtin_amdgcn_s_setprio(1);
#pragma unroll
            for (int i = 0; i < 4; ++i)
#pragma unroll
                for (int j = 0; j < 4; ++j)
                    acc[i][j] = __builtin_amdgcn_mfma_f32_16x16x32_bf16(af[i], bfr[j], acc[i][j], 0, 0, 0);
            __builtin_amdgcn_s_setprio(0);
            __builtin_amdgcn_sched_barrier(0);
            __builtin_amdgcn_s_barrier();
            __builtin_amdgcn_sched_barrier(0);

            // ---------------- phase B: rows 64..127 of wave tile ----------------
            v8s af2[4];
#pragma unroll
            for (int i = 0; i < 4; ++i)
                af2[i] = *(const v8s*)&As[cur][aoff + 2048 + i * 512];
            async16(&Bs[pre][(w * 32) * 32],      Bsrc);
            async16(&Bs[pre][(w * 32 + 16) * 32], Bsrc + 16 * LDB);
            __builtin_amdgcn_s_barrier();
            asm volatile("s_waitcnt lgkmcnt(0)" ::: "memory");
            __builtin_amdgcn_sched_barrier(0);
            __builtin_amdgcn_s_setprio(1);
#pragma unroll
            for (int i = 0; i < 4; ++i)
#pragma unroll
                for (int j = 0; j < 4; ++j)
                    acc[i + 4][j] = __builtin_amdgcn_mfma_f32_16x16x32_bf16(af2[i], bfr[j], acc[i + 4][j], 0, 0, 0);
            __builtin_amdgcn_s_setprio(0);
            // end of K-tile: require tile t+1 landed (its 4 loads are the oldest);
            // tile t+2's 4 loads stay in flight across the barrier (never drain to 0).
            asm volatile("s_waitcnt vmcnt(4)" ::: "memory");
            __builtin_amdgcn_sched_barrier(0);
            __builtin_amdgcn_s_barrier();
            __builtin_amdgcn_sched_barrier(0);
        }
    }

    // epilogue: bias + gelu + bf16 store (i -> r -> j for write combining)
    float bc[4];
#pragma unroll
    for (int j = 0; j < 4; ++j)
        bc[j] = bias[tn + wn * 64 + 16 * j + m16];

#pragma unroll
    for (int i = 0; i < 8; ++i) {
#pragma unroll
        for (int r = 0; r < 4; ++r) {
            int row = tm + wm * 128 + 16 * i + q * 4 + r;
            int rowbase = row * LDC + tn + wn * 64 + m16;
#pragma unroll
            for (int j = 0; j < 4; ++j) {
                float v = acc[i][j][r] + bc[j];
                v = gelu_f(v);
                C[rowbase + 16 * j] = __float2bfloat16(v);
            }
        }
    }
}

// ---------------- attnV: out[b,s,h*64+c] = sum_k P[b,h,s,k] * VT[h*64+c, b*1024+k]
__global__ void __launch_bounds__(256) attnv_kernel(const float* __restrict__ P,
                                                    const bf16* __restrict__ VT,
                                                    bf16* __restrict__ out) {
    __shared__ __align__(16) bf16 As[128 * 32];
    __shared__ __align__(16) bf16 Bs[64 * 32];
    int z = blockIdx.z, b = z >> 4, h = z & 15;
    int tid = threadIdx.x, w = tid >> 6, lane = tid & 63;
    int q = lane >> 4, m16 = lane & 15;
    int srow = lane >> 2, scol = (lane & 3) * 8;

    const float* Ab = P + z * 1048576 + (blockIdx.y * 128 + (tid >> 1)) * 1024 + (tid & 1) * 16;
    const bf16* Bb = VT + (h * 64 + w * 16 + srow) * 4096 + b * 1024 + scol;
    uint4* asd = (uint4*)&As[(tid >> 1) * 32 + (tid & 1) * 16];
    bf16* bsw = &Bs[(w * 16) * 32];

    v4f acc[2][4];
#pragma unroll
    for (int i = 0; i < 2; ++i)
#pragma unroll
        for (int j = 0; j < 4; ++j) acc[i][j] = (v4f){0.f, 0.f, 0.f, 0.f};

#pragma unroll 1
    for (int k0 = 0; k0 < 1024; k0 += 32) {
        const float4* s4 = (const float4*)(Ab + k0);
        float4 f0 = s4[0], f1 = s4[1], f2 = s4[2], f3 = s4[3];
        async16(bsw, Bb + k0);
        uint4 u0, u1;
        u0.x = pk2(f0.x, f0.y); u0.y = pk2(f0.z, f0.w);
        u0.z = pk2(f1.x, f1.y); u0.w = pk2(f1.z, f1.w);
        u1.x = pk2(f2.x, f2.y); u1.y = pk2(f2.z, f2.w);
        u1.z = pk2(f3.x, f3.y); u1.w = pk2(f3.z, f3.w);
        asd[0] = u0; asd[1] = u1;
        __syncthreads();
        v8s af[2], bfr[4];
        af[0] = *(const v8s*)&As[(w * 32 + m16) * 32 + q * 8];
        af[1] = *(const v8s*)&As[(w * 32 + 16 + m16) * 32 + q * 8];
#pragma unroll
        for (int j = 0; j < 4; ++j)
            bfr[j] = *(const v8s*)&Bs[(16 * j + m16) * 32 + q * 8];
#pragma unroll
        for (int i = 0; i < 2; ++i)
#pragma unroll
            for (int j = 0; j < 4; ++j)
                acc[i][j] = __builtin_amdgcn_mfma_f32_16x16x32_bf16(af[i], bfr[j], acc[i][j], 0, 0, 0);
        __syncthreads();
    }

    int orow0 = b * 1024 + blockIdx.y * 128 + w * 32;
#pragma unroll
    for (int i = 0; i < 2; ++i)
#pragma unroll
        for (int r = 0; r < 4; ++r) {
            int row = orow0 + 16 * i + q * 4 + r;
#pragma unroll
            for (int j = 0; j < 4; ++j) {
                int col = h * 64 + 16 * j + m16;
                out[row * 1024 + col] = __float2bfloat16(acc[i][j][r]);
            }
        }
}

// ---------------- host ----------------
extern "C" void kernel_launch(void* const* d_in, const int* in_sizes, int n_in,
                              void* d_out, int out_size, void* d_ws, size_t ws_size,
                              hipStream_t stream) {
    (void)in_sizes; (void)n_in; (void)out_size; (void)ws_size;
    const float* x  = (const float*)d_in[0];
    const float* Wq = (const float*)d_in[1];
    const float* bq = (const float*)d_in[2];
    const float* Wk = (const float*)d_in[3];
    const float* bk = (const float*)d_in[4];
    const float* Wv = (const float*)d_in[5];
    const float* bv = (const float*)d_in[6];
    const float* Wo = (const float*)d_in[7];
    const float* bo = (const float*)d_in[8];
    const float* W1 = (const float*)d_in[9];
    const float* b1 = (const float*)d_in[10];
    const float* Wm = (const float*)d_in[11];
    const float* bm = (const float*)d_in[12];
    const float* W2 = (const float*)d_in[13];
    const float* b2 = (const float*)d_in[14];
    const float* g1 = (const float*)d_in[15];
    const float* be1 = (const float*)d_in[16];
    const float* g2 = (const float*)d_in[17];
    const float* be2 = (const float*)d_in[18];

    char* ws = (char*)d_ws;
    const size_t MB = 1024 * 1024;
    bf16* WQb = (bf16*)(ws + 0 * MB);
    bf16* WKb = (bf16*)(ws + 2 * MB);
    bf16* WVb = (bf16*)(ws + 4 * MB);
    bf16* WOb = (bf16*)(ws + 6 * MB);
    bf16* W1b = (bf16*)(ws + 8 * MB);
    bf16* WMb = (bf16*)(ws + 16 * MB);
    bf16* W2b = (bf16*)(ws + 48 * MB);
    bf16* HB  = (bf16*)(ws + 56 * MB);
    bf16* QB  = (bf16*)(ws + 64 * MB);
    bf16* KB  = (bf16*)(ws + 72 * MB);
    bf16* VT  = (bf16*)(ws + 80 * MB);
    bf16* AT  = (bf16*)(ws + 88 * MB);
    float* X1 = (float*)(ws + 96 * MB);
    bf16* F1  = (bf16*)(ws + 112 * MB);
    bf16* F2  = (bf16*)(ws + 144 * MB);

    float* out_x  = (float*)d_out;
    float* scores = out_x + 4194304;

    F2BP fp;
    fp.src[0] = Wq; fp.dst[0] = WQb; fp.n4[0] = 262144;
    fp.src[1] = Wk; fp.dst[1] = WKb; fp.n4[1] = 262144;
    fp.src[2] = Wv; fp.dst[2] = WVb; fp.n4[2] = 262144;
    fp.src[3] = Wo; fp.dst[3] = WOb; fp.n4[3] = 262144;
    fp.src[4] = W1; fp.dst[4] = W1b; fp.n4[4] = 1048576;
    fp.src[5] = Wm; fp.dst[5] = WMb; fp.n4[5] = 4194304;
    fp.src[6] = W2; fp.dst[6] = W2b; fp.n4[6] = 1048576;
    hipLaunchKernelGGL(f2b_multi, dim3(1024, 7), dim3(256), 0, stream, fp);

    hipLaunchKernelGGL(ln_kernel, dim3(4096), dim3(256), 0, stream, x, g1, be1, HB);

    gemm_t<1024,1024,1024,1024,1024,1,0,0><<<dim3(8,32,1), 256, 0, stream>>>(
        HB, WQb, nullptr, QB, bq, nullptr, 1.f);
    gemm_t<1024,1024,1024,1024,1024,1,0,0><<<dim3(8,32,1), 256, 0, stream>>>(
        HB, WKb, nullptr, KB, bk, nullptr, 1.f);
    gemm_t<1024,1024,1024,4096,4096,2,0,0><<<dim3(32,8,1), 256, 0, stream>>>(
        WVb, HB, nullptr, VT, bv, nullptr, 1.f);

    gemm_t<64,1024,1024,1024,1024,0,0,1><<<dim3(8,8,64), 256, 0, stream>>>(
        QB, KB, scores, nullptr, nullptr, nullptr, 0.125f);

    hipLaunchKernelGGL(topk_softmax, dim3(65536), dim3(256), 0, stream, scores);

    hipLaunchKernelGGL(attnv_kernel, dim3(1,8,64), dim3(256), 0, stream, scores, VT, AT);

    gemm_t<1024,1024,1024,1024,1024,1,0,0><<<dim3(8,32,1), 256, 0, stream>>>(
        AT, WOb, X1, nullptr, bo, x, 1.f);

    hipLaunchKernelGGL(ln_kernel, dim3(4096), dim3(256), 0, stream, X1, g2, be2, HB);

    // FFN: deep-pipelined 256^2 kernels for the two 4096x4096-output GEMMs
    gemm256<1024,1024,1024,4096><<<dim3(16,16,1), 512, 0, stream>>>(HB, W1b, F1, b1);
    gemm256<4096,4096,4096,4096><<<dim3(16,16,1), 512, 0, stream>>>(F1, WMb, F2, bm);

    gemm_t<4096,4096,4096,1024,1024,1,0,0><<<dim3(8,32,1), 256, 0, stream>>>(
        F2, W2b, out_x, nullptr, b2, X1, 1.f);
}

// Round 2
// 1080.402 us; speedup vs baseline: 1.1298x; 1.0555x over previous
//
#include <hip/hip_runtime.h>
#include <hip/hip_bf16.h>

typedef __hip_bfloat16 bf16;
typedef float v4f __attribute__((ext_vector_type(4)));
typedef short v8s __attribute__((ext_vector_type(8)));

#define KSEL 307

__device__ static inline void async16(bf16* lds, const bf16* g) {
    __builtin_amdgcn_global_load_lds(
        (const __attribute__((address_space(1))) void*)g,
        (__attribute__((address_space(3))) void*)lds, 16, 0, 0);
}

__device__ static inline unsigned short f2bu(float f) {
    __hip_bfloat16 h = __float2bfloat16(f);
    return *reinterpret_cast<unsigned short*>(&h);
}

__device__ static inline unsigned pk2(float a, float b) {
    __hip_bfloat162 h = __float22bfloat162_rn(make_float2(a, b));
    return *reinterpret_cast<unsigned*>(&h);
}

// tanh-approx gelu via hardware exp: ~8 VALU ops vs ~35 for erff.
// max abs err ~1e-3, fine vs 0.105 threshold.
__device__ static inline float gelu_f(float v) {
    float c = v * fmaf(v * v, 0.0356774081f, 0.7978845608f);
    return v / (1.0f + __expf(-2.0f * c));
}

// ---------------- fp32 -> bf16 convert, 7 segments in one launch ----------------
struct F2BP { const float* src[7]; bf16* dst[7]; int n4[7]; };

__global__ void __launch_bounds__(256) f2b_multi(F2BP p) {
    int s = blockIdx.y;
    const float* __restrict__ in = p.src[s];
    bf16* __restrict__ out = p.dst[s];
    int n4 = p.n4[s];
    for (int i = blockIdx.x * 256 + threadIdx.x; i < n4; i += gridDim.x * 256) {
        float4 v = ((const float4*)in)[i];
        ushort4 u = make_ushort4(f2bu(v.x), f2bu(v.y), f2bu(v.z), f2bu(v.w));
        ((ushort4*)out)[i] = u;
    }
}

// ---------------- LayerNorm (row of 1024) ----------------
__global__ void __launch_bounds__(256) ln_kernel(const float* __restrict__ x,
                                                 const float* __restrict__ g,
                                                 const float* __restrict__ be,
                                                 bf16* __restrict__ out) {
    int row = blockIdx.x;
    int tid = threadIdx.x;
    const float* xr = x + row * 1024;
    float4 v = ((const float4*)xr)[tid];
    float s = v.x + v.y + v.z + v.w;
    float s2 = v.x*v.x + v.y*v.y + v.z*v.z + v.w*v.w;
    for (int off = 32; off > 0; off >>= 1) {
        s  += __shfl_down(s, off);
        s2 += __shfl_down(s2, off);
    }
    __shared__ float sh[4], sh2[4];
    int w = tid >> 6;
    if ((tid & 63) == 0) { sh[w] = s; sh2[w] = s2; }
    __syncthreads();
    float mean = (sh[0]+sh[1]+sh[2]+sh[3]) * (1.0f / 1024.f);
    float ms   = (sh2[0]+sh2[1]+sh2[2]+sh2[3]) * (1.0f / 1024.f);
    float var  = ms - mean*mean;
    float rs   = rsqrtf(var + 1e-5f);
    float4 gg = ((const float4*)g)[tid];
    float4 bb = ((const float4*)be)[tid];
    ushort4 o = make_ushort4(
        f2bu((v.x-mean)*rs*gg.x + bb.x),
        f2bu((v.y-mean)*rs*gg.y + bb.y),
        f2bu((v.z-mean)*rs*gg.z + bb.z),
        f2bu((v.w-mean)*rs*gg.w + bb.w));
    ((ushort4*)out)[row * 256 + tid] = o;
}

// ---------------- top-k threshold + masked softmax, ONE ROW PER WAVE ----------
// 4 waves/block, wave-private 256-bin LDS histogram, zero __syncthreads.
// Same 16-bit radix-threshold selection semantics as the block-per-row version.
__global__ void __launch_bounds__(256) topk_softmax(float* __restrict__ sc) {
    __shared__ int hist[4][256];
    const int tid = threadIdx.x;
    const int wid = tid >> 6, lane = tid & 63;
    float* p = sc + ((long long)blockIdx.x * 4 + wid) * 1024;
    int* h = hist[wid];

    // lane l owns elements l*4 + j*256 + i (i=0..3, j=0..3): each float4 load
    // is a contiguous 1KB wave access.
    float v[16];
    unsigned key[16];
#pragma unroll
    for (int j = 0; j < 4; ++j) {
        float4 t = *(const float4*)(p + lane * 4 + j * 256);
        v[j*4+0] = t.x; v[j*4+1] = t.y; v[j*4+2] = t.z; v[j*4+3] = t.w;
    }
#pragma unroll
    for (int j = 0; j < 16; ++j) {
        unsigned u = __float_as_uint(v[j]);
        key[j] = (u & 0x80000000u) ? ~u : (u | 0x80000000u);
    }

    unsigned prefix = 0;
    int need = KSEL;
#pragma unroll
    for (int pass = 0; pass < 2; ++pass) {
        const int shift = 24 - 8 * pass;
        // zero wave-private hist (ds ops of one wave execute in order)
        *(int4*)&h[lane * 4] = make_int4(0, 0, 0, 0);
        asm volatile("s_waitcnt lgkmcnt(0)" ::: "memory");
#pragma unroll
        for (int j = 0; j < 16; ++j) {
            bool cand = (pass == 0) || ((key[j] >> 24) == prefix);
            if (cand) atomicAdd(&h[(key[j] >> shift) & 255], 1);
        }
        asm volatile("s_waitcnt lgkmcnt(0)" ::: "memory");
        int4 hc = *(const int4*)&h[lane * 4];
        int s_local = hc.x + hc.y + hc.z + hc.w;
        // inclusive suffix scan across lanes: sfx = sum of bins >= lane*4
        int sfx = s_local;
#pragma unroll
        for (int off = 1; off < 64; off <<= 1) {
            int o = __shfl_down(sfx, off);
            if (lane + off < 64) sfx += o;
        }
        int sfx_next = __shfl_down(sfx, 1);
        if (lane == 63) sfx_next = 0;
        int above_lane = sfx - s_local;          // sum of bins > lane*4+3
        int suf3 = above_lane + hc.w;
        int suf2 = suf3 + hc.z;
        int suf1 = suf2 + hc.y;
        int suf0 = suf1 + hc.x;                  // == sfx
        // unique crossing: largest bin b with suf(b) >= need, suf(b+1) < need
        int bloc = -1, abv = 0;
        if (suf0 >= need && suf1 < need)     { bloc = lane*4+0; abv = suf1; }
        if (suf1 >= need && suf2 < need)     { bloc = lane*4+1; abv = suf2; }
        if (suf2 >= need && suf3 < need)     { bloc = lane*4+2; abv = suf3; }
        if (suf3 >= need && sfx_next < need) { bloc = lane*4+3; abv = sfx_next; }
        unsigned long long mask = __ballot(bloc >= 0);
        int src = __ffsll((unsigned long long)mask) - 1;
        int b = __shfl(bloc, src);
        int above = __shfl(abv, src);
        prefix = (prefix << 8) | (unsigned)b;
        need -= above;
    }

    // softmax over selected (key>>16 >= prefix); max is always selected
    float mx = v[0];
#pragma unroll
    for (int j = 1; j < 16; ++j) mx = fmaxf(mx, v[j]);
#pragma unroll
    for (int off = 32; off > 0; off >>= 1) mx = fmaxf(mx, __shfl_xor(mx, off));
    float sum = 0.f;
#pragma unroll
    for (int j = 0; j < 16; ++j) {
        bool sel = (key[j] >> 16) >= prefix;
        v[j] = sel ? __expf(v[j] - mx) : 0.f;    // overwrite v -> fewer VGPRs
        sum += v[j];
    }
#pragma unroll
    for (int off = 32; off > 0; off >>= 1) sum += __shfl_xor(sum, off);
    float inv = 1.0f / sum;
#pragma unroll
    for (int j = 0; j < 4; ++j) {
        float4 o;
        o.x = v[j*4+0]*inv; o.y = v[j*4+1]*inv; o.z = v[j*4+2]*inv; o.w = v[j*4+3]*inv;
        *(float4*)(p + lane * 4 + j * 256) = o;
    }
}

// ---------------- templated BT GEMM (128x128 tile): used for QKV/Wo/W2/QK^T ----
template<int K, int LDA, int LDB, int LDC, int N, int BMODE, int ACT, int BM>
__global__ void __launch_bounds__(256) gemm_t(const bf16* __restrict__ A,
                                              const bf16* __restrict__ B,
                                              float* __restrict__ Cf,
                                              bf16* __restrict__ Cb,
                                              const float* __restrict__ bias,
                                              const float* __restrict__ resid,
                                              float scale) {
    __shared__ __align__(16) bf16 As[128 * 32];
    __shared__ __align__(16) bf16 Bs[128 * 32];
    int offA = 0, offB = 0, offC = 0;
    if (BM == 1) {
        int z = blockIdx.z;
        int b = z >> 4, h = z & 15;
        offA = b * 1048576 + h * 64;
        offB = offA;
        offC = z * 1048576;
    }
    const int tid = threadIdx.x;
    const int w = tid >> 6, lane = tid & 63;
    const int tm = blockIdx.y * 128, tn = blockIdx.x * 128;
    const int q = lane >> 4, m16 = lane & 15;
    const int r0 = (w >> 1) * 64, c0 = (w & 1) * 64;
    const int srow = lane >> 2, scol = (lane & 3) * 8;

    v4f acc[4][4];
#pragma unroll
    for (int i = 0; i < 4; ++i)
#pragma unroll
        for (int j = 0; j < 4; ++j) acc[i][j] = (v4f){0.f, 0.f, 0.f, 0.f};

    const bf16* Ab = A + offA + (tm + w * 16 + srow) * LDA + scol;
    const bf16* Bb = B + offB + (tn + w * 16 + srow) * LDB + scol;
    bf16* Asw = &As[(w * 16) * 32];
    bf16* Bsw = &Bs[(w * 16) * 32];

#pragma unroll 1
    for (int k0 = 0; k0 < K; k0 += 32) {
        async16(Asw,           Ab + k0);
        async16(Asw + 64 * 32, Ab + 64 * LDA + k0);
        async16(Bsw,           Bb + k0);
        async16(Bsw + 64 * 32, Bb + 64 * LDB + k0);
        __syncthreads();
        v8s af[4], bfr[4];
#pragma unroll
        for (int i = 0; i < 4; ++i)
            af[i] = *(const v8s*)&As[(r0 + 16 * i + m16) * 32 + q * 8];
#pragma unroll
        for (int j = 0; j < 4; ++j)
            bfr[j] = *(const v8s*)&Bs[(c0 + 16 * j + m16) * 32 + q * 8];
#pragma unroll
        for (int i = 0; i < 4; ++i)
#pragma unroll
            for (int j = 0; j < 4; ++j)
                acc[i][j] = __builtin_amdgcn_mfma_f32_16x16x32_bf16(af[i], bfr[j], acc[i][j], 0, 0, 0);
        __syncthreads();
    }

    float bc[4];
#pragma unroll
    for (int j = 0; j < 4; ++j)
        bc[j] = (BMODE == 1) ? bias[tn + c0 + 16 * j + m16] : 0.f;

#pragma unroll
    for (int i = 0; i < 4; ++i) {
#pragma unroll
        for (int r = 0; r < 4; ++r) {
            int row = tm + r0 + 16 * i + q * 4 + r;
            float br = (BMODE == 2) ? bias[row] : 0.f;
            int rowbase = offC + row * LDC + tn + c0 + m16;
#pragma unroll
            for (int j = 0; j < 4; ++j) {
                float v = acc[i][j][r] * scale + bc[j] + br;
                if (ACT) v = gelu_f(v);
                int idx = rowbase + 16 * j;
                if (resid) v += resid[idx];
                if (Cf) Cf[idx] = v;
                if (Cb) Cb[idx] = __float2bfloat16(v);
            }
        }
    }
}

// ---------------- 256x256 deep-pipelined GEMM (W1, Wm): 8 waves, BK=32,
// 4-deep LDS ring, counted vmcnt(4), per-phase barrier+setprio interleave.
// C[m,n] = gelu(sum_k A[m,k]*B[n,k] + bias[n]), bf16 out.
template<int K, int LDA, int LDB, int LDC>
__global__ void __launch_bounds__(512, 2) gemm256(const bf16* __restrict__ A,
                                                  const bf16* __restrict__ B,
                                                  bf16* __restrict__ C,
                                                  const float* __restrict__ bias) {
    // ring of 4 K-tiles: 4 * (256x32 A + 256x32 B) bf16 = 128 KiB
    __shared__ __align__(16) bf16 As[4][256 * 32];
    __shared__ __align__(16) bf16 Bs[4][256 * 32];

    constexpr int nt = K / 32;
    static_assert(nt >= 4 && (nt % 4) == 0, "K must be multiple of 128");

    const int tid = threadIdx.x;
    const int w = tid >> 6, lane = tid & 63;
    const int wm = w >> 2, wn = w & 3;          // 2 x 4 wave grid
    const int q = lane >> 4, m16 = lane & 15;

    // XCD-chunked remap of the 16x16 grid: XCD x owns a 4-row x 8-col tile region
    // (256 blocks, 256 CUs, 1 block/CU; HW round-robins dispatch index over 8 XCDs).
    int bid = blockIdx.y * 16 + blockIdx.x;
    int xcd = bid & 7, inner = bid >> 3;
    int by = (xcd & 3) * 4 + (inner & 3);
    int bx = (xcd >> 2) * 8 + (inner >> 2);
    const int tm = by * 256, tn = bx * 256;

    // staging: wave w owns rows [w*32, w*32+32) of each 256-row tile; two
    // global_load_lds(16B) per tile-half; LDS dest is wave-uniform base + lane*16.
    const int srow = lane >> 2;            // 0..15
    const int scol = (lane & 3) * 8;       // 0,8,16,24 (bf16 elems = 16B chunks)
    const bf16* Ag = A + (tm + w * 32 + srow) * LDA + scol;
    const bf16* Bg = B + (tn + w * 32 + srow) * LDB + scol;

    v4f acc[8][4];
#pragma unroll
    for (int i = 0; i < 8; ++i)
#pragma unroll
        for (int j = 0; j < 4; ++j) acc[i][j] = (v4f){0.f, 0.f, 0.f, 0.f};

    // fragment read offsets (elements). BK=32 rows are 64B -> ds_read_b128 of a
    // 16-row fragment group is naturally bank-uniform (8 lanes per 16B slot).
    const int aoff = (wm * 128 + m16) * 32 + q * 8;
    const int boff = (wn * 64 + m16) * 32 + q * 8;

    // ---- prologue: stage K-tiles 0,1 into ring slots 0,1 (8 loads/wave) ----
#pragma unroll
    for (int t = 0; t < 2; ++t) {
        async16(&As[t][(w * 32) * 32],      Ag + t * 32);
        async16(&As[t][(w * 32 + 16) * 32], Ag + 16 * LDA + t * 32);
        async16(&Bs[t][(w * 32) * 32],      Bg + t * 32);
        async16(&Bs[t][(w * 32 + 16) * 32], Bg + 16 * LDB + t * 32);
    }
    asm volatile("s_waitcnt vmcnt(4)" ::: "memory");   // tile 0 landed; tile 1 in flight
    __builtin_amdgcn_s_barrier();
    __builtin_amdgcn_sched_barrier(0);

#pragma unroll 1
    for (int t4 = 0; t4 < nt; t4 += 4) {
#pragma unroll
        for (int tt = 0; tt < 4; ++tt) {
            const int t = t4 + tt;
            const int cur = tt;                 // ring slot being computed
            const int pre = (tt + 2) & 3;       // ring slot being staged (t+2)
            int kt = t + 2; if (kt >= nt) kt = 0;   // clamp: dead staging at tail
            const bf16* Asrc = Ag + kt * 32;
            const bf16* Bsrc = Bg + kt * 32;

            // ---------------- phase A: rows 0..63 of wave tile ----------------
            v8s af[4], bfr[4];
#pragma unroll
            for (int i = 0; i < 4; ++i)
                af[i] = *(const v8s*)&As[cur][aoff + i * 512];
#pragma unroll
            for (int j = 0; j < 4; ++j)
                bfr[j] = *(const v8s*)&Bs[cur][boff + j * 512];
            async16(&As[pre][(w * 32) * 32],      Asrc);
            async16(&As[pre][(w * 32 + 16) * 32], Asrc + 16 * LDA);
            __builtin_amdgcn_s_barrier();
            asm volatile("s_waitcnt lgkmcnt(0)" ::: "memory");
            __builtin_amdgcn_sched_barrier(0);
            __builtin_amdgcn_s_setprio(1);
#pragma unroll
            for (int i = 0; i < 4; ++i)
#pragma unroll
                for (int j = 0; j < 4; ++j)
                    acc[i][j] = __builtin_amdgcn_mfma_f32_16x16x32_bf16(af[i], bfr[j], acc[i][j], 0, 0, 0);
            __builtin_amdgcn_s_setprio(0);
            __builtin_amdgcn_sched_barrier(0);
            __builtin_amdgcn_s_barrier();
            __builtin_amdgcn_sched_barrier(0);

            // ---------------- phase B: rows 64..127 of wave tile ----------------
            v8s af2[4];
#pragma unroll
            for (int i = 0; i < 4; ++i)
                af2[i] = *(const v8s*)&As[cur][aoff + 2048 + i * 512];
            async16(&Bs[pre][(w * 32) * 32],      Bsrc);
            async16(&Bs[pre][(w * 32 + 16) * 32], Bsrc + 16 * LDB);
            __builtin_amdgcn_s_barrier();
            asm volatile("s_waitcnt lgkmcnt(0)" ::: "memory");
            __builtin_amdgcn_sched_barrier(0);
            __builtin_amdgcn_s_setprio(1);
#pragma unroll
            for (int i = 0; i < 4; ++i)
#pragma unroll
                for (int j = 0; j < 4; ++j)
                    acc[i + 4][j] = __builtin_amdgcn_mfma_f32_16x16x32_bf16(af2[i], bfr[j], acc[i + 4][j], 0, 0, 0);
            __builtin_amdgcn_s_setprio(0);
            // end of K-tile: require tile t+1 landed (its 4 loads are the oldest);
            // tile t+2's 4 loads stay in flight across the barrier (never drain to 0).
            asm volatile("s_waitcnt vmcnt(4)" ::: "memory");
            __builtin_amdgcn_sched_barrier(0);
            __builtin_amdgcn_s_barrier();
            __builtin_amdgcn_sched_barrier(0);
        }
    }

    // epilogue: bias + gelu + bf16 store (i -> r -> j for write combining)
    float bc[4];
#pragma unroll
    for (int j = 0; j < 4; ++j)
        bc[j] = bias[tn + wn * 64 + 16 * j + m16];

#pragma unroll
    for (int i = 0; i < 8; ++i) {
#pragma unroll
        for (int r = 0; r < 4; ++r) {
            int row = tm + wm * 128 + 16 * i + q * 4 + r;
            int rowbase = row * LDC + tn + wn * 64 + m16;
#pragma unroll
            for (int j = 0; j < 4; ++j) {
                float v = acc[i][j][r] + bc[j];
                v = gelu_f(v);
                C[rowbase + 16 * j] = __float2bfloat16(v);
            }
        }
    }
}

// ---------------- attnV: out[b,s,h*64+c] = sum_k P[b,h,s,k] * VT[h*64+c, b*1024+k]
__global__ void __launch_bounds__(256) attnv_kernel(const float* __restrict__ P,
                                                    const bf16* __restrict__ VT,
                                                    bf16* __restrict__ out) {
    __shared__ __align__(16) bf16 As[128 * 32];
    __shared__ __align__(16) bf16 Bs[64 * 32];
    int z = blockIdx.z, b = z >> 4, h = z & 15;
    int tid = threadIdx.x, w = tid >> 6, lane = tid & 63;
    int q = lane >> 4, m16 = lane & 15;
    int srow = lane >> 2, scol = (lane & 3) * 8;

    const float* Ab = P + z * 1048576 + (blockIdx.y * 128 + (tid >> 1)) * 1024 + (tid & 1) * 16;
    const bf16* Bb = VT + (h * 64 + w * 16 + srow) * 4096 + b * 1024 + scol;
    uint4* asd = (uint4*)&As[(tid >> 1) * 32 + (tid & 1) * 16];
    bf16* bsw = &Bs[(w * 16) * 32];

    v4f acc[2][4];
#pragma unroll
    for (int i = 0; i < 2; ++i)
#pragma unroll
        for (int j = 0; j < 4; ++j) acc[i][j] = (v4f){0.f, 0.f, 0.f, 0.f};

#pragma unroll 1
    for (int k0 = 0; k0 < 1024; k0 += 32) {
        const float4* s4 = (const float4*)(Ab + k0);
        float4 f0 = s4[0], f1 = s4[1], f2 = s4[2], f3 = s4[3];
        async16(bsw, Bb + k0);
        uint4 u0, u1;
        u0.x = pk2(f0.x, f0.y); u0.y = pk2(f0.z, f0.w);
        u0.z = pk2(f1.x, f1.y); u0.w = pk2(f1.z, f1.w);
        u1.x = pk2(f2.x, f2.y); u1.y = pk2(f2.z, f2.w);
        u1.z = pk2(f3.x, f3.y); u1.w = pk2(f3.z, f3.w);
        asd[0] = u0; asd[1] = u1;
        __syncthreads();
        v8s af[2], bfr[4];
        af[0] = *(const v8s*)&As[(w * 32 + m16) * 32 + q * 8];
        af[1] = *(const v8s*)&As[(w * 32 + 16 + m16) * 32 + q * 8];
#pragma unroll
        for (int j = 0; j < 4; ++j)
            bfr[j] = *(const v8s*)&Bs[(16 * j + m16) * 32 + q * 8];
#pragma unroll
        for (int i = 0; i < 2; ++i)
#pragma unroll
            for (int j = 0; j < 4; ++j)
                acc[i][j] = __builtin_amdgcn_mfma_f32_16x16x32_bf16(af[i], bfr[j], acc[i][j], 0, 0, 0);
        __syncthreads();
    }

    int orow0 = b * 1024 + blockIdx.y * 128 + w * 32;
#pragma unroll
    for (int i = 0; i < 2; ++i)
#pragma unroll
        for (int r = 0; r < 4; ++r) {
            int row = orow0 + 16 * i + q * 4 + r;
#pragma unroll
            for (int j = 0; j < 4; ++j) {
                int col = h * 64 + 16 * j + m16;
                out[row * 1024 + col] = __float2bfloat16(acc[i][j][r]);
            }
        }
}

// ---------------- host ----------------
extern "C" void kernel_launch(void* const* d_in, const int* in_sizes, int n_in,
                              void* d_out, int out_size, void* d_ws, size_t ws_size,
                              hipStream_t stream) {
    (void)in_sizes; (void)n_in; (void)out_size; (void)ws_size;
    const float* x  = (const float*)d_in[0];
    const float* Wq = (const float*)d_in[1];
    const float* bq = (const float*)d_in[2];
    const float* Wk = (const float*)d_in[3];
    const float* bk = (const float*)d_in[4];
    const float* Wv = (const float*)d_in[5];
    const float* bv = (const float*)d_in[6];
    const float* Wo = (const float*)d_in[7];
    const float* bo = (const float*)d_in[8];
    const float* W1 = (const float*)d_in[9];
    const float* b1 = (const float*)d_in[10];
    const float* Wm = (const float*)d_in[11];
    const float* bm = (const float*)d_in[12];
    const float* W2 = (const float*)d_in[13];
    const float* b2 = (const float*)d_in[14];
    const float* g1 = (const float*)d_in[15];
    const float* be1 = (const float*)d_in[16];
    const float* g2 = (const float*)d_in[17];
    const float* be2 = (const float*)d_in[18];

    char* ws = (char*)d_ws;
    const size_t MB = 1024 * 1024;
    bf16* WQb = (bf16*)(ws + 0 * MB);
    bf16* WKb = (bf16*)(ws + 2 * MB);
    bf16* WVb = (bf16*)(ws + 4 * MB);
    bf16* WOb = (bf16*)(ws + 6 * MB);
    bf16* W1b = (bf16*)(ws + 8 * MB);
    bf16* WMb = (bf16*)(ws + 16 * MB);
    bf16* W2b = (bf16*)(ws + 48 * MB);
    bf16* HB  = (bf16*)(ws + 56 * MB);
    bf16* QB  = (bf16*)(ws + 64 * MB);
    bf16* KB  = (bf16*)(ws + 72 * MB);
    bf16* VT  = (bf16*)(ws + 80 * MB);
    bf16* AT  = (bf16*)(ws + 88 * MB);
    float* X1 = (float*)(ws + 96 * MB);
    bf16* F1  = (bf16*)(ws + 112 * MB);
    bf16* F2  = (bf16*)(ws + 144 * MB);

    float* out_x  = (float*)d_out;
    float* scores = out_x + 4194304;

    F2BP fp;
    fp.src[0] = Wq; fp.dst[0] = WQb; fp.n4[0] = 262144;
    fp.src[1] = Wk; fp.dst[1] = WKb; fp.n4[1] = 262144;
    fp.src[2] = Wv; fp.dst[2] = WVb; fp.n4[2] = 262144;
    fp.src[3] = Wo; fp.dst[3] = WOb; fp.n4[3] = 262144;
    fp.src[4] = W1; fp.dst[4] = W1b; fp.n4[4] = 1048576;
    fp.src[5] = Wm; fp.dst[5] = WMb; fp.n4[5] = 4194304;
    fp.src[6] = W2; fp.dst[6] = W2b; fp.n4[6] = 1048576;
    hipLaunchKernelGGL(f2b_multi, dim3(1024, 7), dim3(256), 0, stream, fp);

    hipLaunchKernelGGL(ln_kernel, dim3(4096), dim3(256), 0, stream, x, g1, be1, HB);

    gemm_t<1024,1024,1024,1024,1024,1,0,0><<<dim3(8,32,1), 256, 0, stream>>>(
        HB, WQb, nullptr, QB, bq, nullptr, 1.f);
    gemm_t<1024,1024,1024,1024,1024,1,0,0><<<dim3(8,32,1), 256, 0, stream>>>(
        HB, WKb, nullptr, KB, bk, nullptr, 1.f);
    gemm_t<1024,1024,1024,4096,4096,2,0,0><<<dim3(32,8,1), 256, 0, stream>>>(
        WVb, HB, nullptr, VT, bv, nullptr, 1.f);

    gemm_t<64,1024,1024,1024,1024,0,0,1><<<dim3(8,8,64), 256, 0, stream>>>(
        QB, KB, scores, nullptr, nullptr, nullptr, 0.125f);

    hipLaunchKernelGGL(topk_softmax, dim3(16384), dim3(256), 0, stream, scores);

    hipLaunchKernelGGL(attnv_kernel, dim3(1,8,64), dim3(256), 0, stream, scores, VT, AT);

    gemm_t<1024,1024,1024,1024,1024,1,0,0><<<dim3(8,32,1), 256, 0, stream>>>(
        AT, WOb, X1, nullptr, bo, x, 1.f);

    hipLaunchKernelGGL(ln_kernel, dim3(4096), dim3(256), 0, stream, X1, g2, be2, HB);

    // FFN: deep-pipelined 256^2 kernels for the two 4096x4096-output GEMMs
    gemm256<1024,1024,1024,4096><<<dim3(16,16,1), 512, 0, stream>>>(HB, W1b, F1, b1);
    gemm256<4096,4096,4096,4096><<<dim3(16,16,1), 512, 0, stream>>>(F1, WMb, F2, bm);

    gemm_t<4096,4096,4096,1024,1024,1,0,0><<<dim3(8,32,1), 256, 0, stream>>>(
        F2, W2b, out_x, nullptr, b2, X1, 1.f);
}

// Round 3
// 1057.534 us; speedup vs baseline: 1.1542x; 1.0216x over previous
//
#include <hip/hip_runtime.h>
#include <hip/hip_bf16.h>

typedef __hip_bfloat16 bf16;
typedef float v4f __attribute__((ext_vector_type(4)));
typedef short v8s __attribute__((ext_vector_type(8)));

#define KSEL 307

__device__ static inline void async16(bf16* lds, const bf16* g) {
    __builtin_amdgcn_global_load_lds(
        (const __attribute__((address_space(1))) void*)g,
        (__attribute__((address_space(3))) void*)lds, 16, 0, 0);
}

__device__ static inline unsigned short f2bu(float f) {
    __hip_bfloat16 h = __float2bfloat16(f);
    return *reinterpret_cast<unsigned short*>(&h);
}

__device__ static inline unsigned pk2(float a, float b) {
    __hip_bfloat162 h = __float22bfloat162_rn(make_float2(a, b));
    return *reinterpret_cast<unsigned*>(&h);
}

// tanh-approx gelu via hardware exp: ~8 VALU ops vs ~35 for erff.
// max abs err ~1e-3, fine vs 0.105 threshold.
__device__ static inline float gelu_f(float v) {
    float c = v * fmaf(v * v, 0.0356774081f, 0.7978845608f);
    return v / (1.0f + __expf(-2.0f * c));
}

// ---------------- fp32 -> bf16 convert, 7 segments in one launch ----------------
struct F2BP { const float* src[7]; bf16* dst[7]; int n4[7]; };

__global__ void __launch_bounds__(256) f2b_multi(F2BP p) {
    int s = blockIdx.y;
    const float* __restrict__ in = p.src[s];
    bf16* __restrict__ out = p.dst[s];
    int n4 = p.n4[s];
    for (int i = blockIdx.x * 256 + threadIdx.x; i < n4; i += gridDim.x * 256) {
        float4 v = ((const float4*)in)[i];
        ushort4 u = make_ushort4(f2bu(v.x), f2bu(v.y), f2bu(v.z), f2bu(v.w));
        ((ushort4*)out)[i] = u;
    }
}

// ---------------- LayerNorm (row of 1024) ----------------
__global__ void __launch_bounds__(256) ln_kernel(const float* __restrict__ x,
                                                 const float* __restrict__ g,
                                                 const float* __restrict__ be,
                                                 bf16* __restrict__ out) {
    int row = blockIdx.x;
    int tid = threadIdx.x;
    const float* xr = x + row * 1024;
    float4 v = ((const float4*)xr)[tid];
    float s = v.x + v.y + v.z + v.w;
    float s2 = v.x*v.x + v.y*v.y + v.z*v.z + v.w*v.w;
    for (int off = 32; off > 0; off >>= 1) {
        s  += __shfl_down(s, off);
        s2 += __shfl_down(s2, off);
    }
    __shared__ float sh[4], sh2[4];
    int w = tid >> 6;
    if ((tid & 63) == 0) { sh[w] = s; sh2[w] = s2; }
    __syncthreads();
    float mean = (sh[0]+sh[1]+sh[2]+sh[3]) * (1.0f / 1024.f);
    float ms   = (sh2[0]+sh2[1]+sh2[2]+sh2[3]) * (1.0f / 1024.f);
    float var  = ms - mean*mean;
    float rs   = rsqrtf(var + 1e-5f);
    float4 gg = ((const float4*)g)[tid];
    float4 bb = ((const float4*)be)[tid];
    ushort4 o = make_ushort4(
        f2bu((v.x-mean)*rs*gg.x + bb.x),
        f2bu((v.y-mean)*rs*gg.y + bb.y),
        f2bu((v.z-mean)*rs*gg.z + bb.z),
        f2bu((v.w-mean)*rs*gg.w + bb.w));
    ((ushort4*)out)[row * 256 + tid] = o;
}

// ---------------- top-k threshold + masked softmax, ONE ROW PER WAVE ----------
// Input: bf16 scores (16-bit radix keys = exactly the old selection granularity).
// Output: fp32 probs. 4 waves/block, wave-private histogram, zero __syncthreads.
__global__ void __launch_bounds__(256) topk_softmax(const unsigned short* __restrict__ scb,
                                                    float* __restrict__ out) {
    __shared__ int hist[4][256];
    const int tid = threadIdx.x;
    const int wid = tid >> 6, lane = tid & 63;
    const long long row = (long long)blockIdx.x * 4 + wid;
    const unsigned short* pb = scb + row * 1024;
    float* po = out + row * 1024;
    int* h = hist[wid];

    // lane l owns elements l*4 + j*256 + i (i=0..3, j=0..3): contiguous wave loads.
    unsigned short raw[16];
    unsigned key[16];
    float v[16];
#pragma unroll
    for (int j = 0; j < 4; ++j) {
        ushort4 t = *(const ushort4*)(pb + lane * 4 + j * 256);
        raw[j*4+0] = t.x; raw[j*4+1] = t.y; raw[j*4+2] = t.z; raw[j*4+3] = t.w;
    }
#pragma unroll
    for (int j = 0; j < 16; ++j) {
        unsigned u = raw[j];
        key[j] = (u & 0x8000u) ? (0xFFFFu & ~u) : (u | 0x8000u);
        v[j] = __uint_as_float(u << 16);            // exact bf16 -> f32
    }

    unsigned prefix = 0;
    int need = KSEL;
#pragma unroll
    for (int pass = 0; pass < 2; ++pass) {
        const int shift = 8 - 8 * pass;
        *(int4*)&h[lane * 4] = make_int4(0, 0, 0, 0);
        asm volatile("s_waitcnt lgkmcnt(0)" ::: "memory");
#pragma unroll
        for (int j = 0; j < 16; ++j) {
            bool cand = (pass == 0) || ((key[j] >> 8) == prefix);
            if (cand) atomicAdd(&h[(key[j] >> shift) & 255], 1);
        }
        asm volatile("s_waitcnt lgkmcnt(0)" ::: "memory");
        int4 hc = *(const int4*)&h[lane * 4];
        int s_local = hc.x + hc.y + hc.z + hc.w;
        // inclusive suffix scan across lanes: sfx = sum of bins >= lane*4
        int sfx = s_local;
#pragma unroll
        for (int off = 1; off < 64; off <<= 1) {
            int o = __shfl_down(sfx, off);
            if (lane + off < 64) sfx += o;
        }
        int sfx_next = __shfl_down(sfx, 1);
        if (lane == 63) sfx_next = 0;
        int above_lane = sfx - s_local;          // sum of bins > lane*4+3
        int suf3 = above_lane + hc.w;
        int suf2 = suf3 + hc.z;
        int suf1 = suf2 + hc.y;
        int suf0 = suf1 + hc.x;                  // == sfx
        // unique crossing: largest bin b with suf(b) >= need, suf(b+1) < need
        int bloc = -1, abv = 0;
        if (suf0 >= need && suf1 < need)     { bloc = lane*4+0; abv = suf1; }
        if (suf1 >= need && suf2 < need)     { bloc = lane*4+1; abv = suf2; }
        if (suf2 >= need && suf3 < need)     { bloc = lane*4+2; abv = suf3; }
        if (suf3 >= need && sfx_next < need) { bloc = lane*4+3; abv = sfx_next; }
        unsigned long long mask = __ballot(bloc >= 0);
        int src = __ffsll((unsigned long long)mask) - 1;
        int b = __shfl(bloc, src);
        int above = __shfl(abv, src);
        prefix = (prefix << 8) | (unsigned)b;
        need -= above;
    }

    // softmax over selected (key >= prefix); max is always selected
    float mx = v[0];
#pragma unroll
    for (int j = 1; j < 16; ++j) mx = fmaxf(mx, v[j]);
#pragma unroll
    for (int off = 32; off > 0; off >>= 1) mx = fmaxf(mx, __shfl_xor(mx, off));
    float sum = 0.f;
#pragma unroll
    for (int j = 0; j < 16; ++j) {
        bool sel = key[j] >= prefix;
        v[j] = sel ? __expf(v[j] - mx) : 0.f;
        sum += v[j];
    }
#pragma unroll
    for (int off = 32; off > 0; off >>= 1) sum += __shfl_xor(sum, off);
    float inv = 1.0f / sum;
#pragma unroll
    for (int j = 0; j < 4; ++j) {
        float4 o;
        o.x = v[j*4+0]*inv; o.y = v[j*4+1]*inv; o.z = v[j*4+2]*inv; o.w = v[j*4+3]*inv;
        *(float4*)(po + lane * 4 + j * 256) = o;
    }
}

// ---------------- templated BT GEMM (128x128 tile): used for QKV/Wo/W2/QK^T ----
// T2 XOR-swizzle: LDS dest stays linear (global_load_lds requirement); the global
// SOURCE chunk is pre-permuted (scol ^= row-bits) and the fragment read applies
// the same XOR -> 8-way bank conflict on ds_read_b128 becomes 2-way (free).
template<int K, int LDA, int LDB, int LDC, int N, int BMODE, int ACT, int BM>
__global__ void __launch_bounds__(256) gemm_t(const bf16* __restrict__ A,
                                              const bf16* __restrict__ B,
                                              float* __restrict__ Cf,
                                              bf16* __restrict__ Cb,
                                              const float* __restrict__ bias,
                                              const float* __restrict__ resid,
                                              float scale) {
    __shared__ __align__(16) bf16 As[128 * 32];
    __shared__ __align__(16) bf16 Bs[128 * 32];
    int offA = 0, offB = 0, offC = 0;
    if (BM == 1) {
        int z = blockIdx.z;
        int b = z >> 4, h = z & 15;
        offA = b * 1048576 + h * 64;
        offB = offA;
        offC = z * 1048576;
    }
    const int tid = threadIdx.x;
    const int w = tid >> 6, lane = tid & 63;
    const int tm = blockIdx.y * 128, tn = blockIdx.x * 128;
    const int q = lane >> 4, m16 = lane & 15;
    const int r0 = (w >> 1) * 64, c0 = (w & 1) * 64;
    // staging: srow = lane>>2; source chunk pre-swizzled by row bits 2:1
    const int srow = lane >> 2;
    const int scol = ((lane & 3) ^ ((lane >> 3) & 3)) * 8;
    // fragment read: same XOR on the k-chunk index
    const int sq = q ^ ((m16 >> 1) & 3);

    v4f acc[4][4];
#pragma unroll
    for (int i = 0; i < 4; ++i)
#pragma unroll
        for (int j = 0; j < 4; ++j) acc[i][j] = (v4f){0.f, 0.f, 0.f, 0.f};

    const bf16* Ab = A + offA + (tm + w * 16 + srow) * LDA + scol;
    const bf16* Bb = B + offB + (tn + w * 16 + srow) * LDB + scol;
    bf16* Asw = &As[(w * 16) * 32];
    bf16* Bsw = &Bs[(w * 16) * 32];

#pragma unroll 1
    for (int k0 = 0; k0 < K; k0 += 32) {
        async16(Asw,           Ab + k0);
        async16(Asw + 64 * 32, Ab + 64 * LDA + k0);
        async16(Bsw,           Bb + k0);
        async16(Bsw + 64 * 32, Bb + 64 * LDB + k0);
        __syncthreads();
        v8s af[4], bfr[4];
#pragma unroll
        for (int i = 0; i < 4; ++i)
            af[i] = *(const v8s*)&As[(r0 + 16 * i + m16) * 32 + sq * 8];
#pragma unroll
        for (int j = 0; j < 4; ++j)
            bfr[j] = *(const v8s*)&Bs[(c0 + 16 * j + m16) * 32 + sq * 8];
#pragma unroll
        for (int i = 0; i < 4; ++i)
#pragma unroll
            for (int j = 0; j < 4; ++j)
                acc[i][j] = __builtin_amdgcn_mfma_f32_16x16x32_bf16(af[i], bfr[j], acc[i][j], 0, 0, 0);
        __syncthreads();
    }

    float bc[4];
#pragma unroll
    for (int j = 0; j < 4; ++j)
        bc[j] = (BMODE == 1) ? bias[tn + c0 + 16 * j + m16] : 0.f;

#pragma unroll
    for (int i = 0; i < 4; ++i) {
#pragma unroll
        for (int r = 0; r < 4; ++r) {
            int row = tm + r0 + 16 * i + q * 4 + r;
            float br = (BMODE == 2) ? bias[row] : 0.f;
            int rowbase = offC + row * LDC + tn + c0 + m16;
#pragma unroll
            for (int j = 0; j < 4; ++j) {
                float v = acc[i][j][r] * scale + bc[j] + br;
                if (ACT) v = gelu_f(v);
                int idx = rowbase + 16 * j;
                if (resid) v += resid[idx];
                if (Cf) Cf[idx] = v;
                if (Cb) Cb[idx] = __float2bfloat16(v);
            }
        }
    }
}

// ---------------- 256x256 deep-pipelined GEMM (W1, Wm): 8 waves, BK=32,
// 4-deep LDS ring, counted vmcnt(4), per-phase barrier+setprio interleave,
// T2 XOR-swizzle (pre-swizzled source + swizzled ds_read).
// C[m,n] = gelu(sum_k A[m,k]*B[n,k] + bias[n]), bf16 out.
template<int K, int LDA, int LDB, int LDC>
__global__ void __launch_bounds__(512, 2) gemm256(const bf16* __restrict__ A,
                                                  const bf16* __restrict__ B,
                                                  bf16* __restrict__ C,
                                                  const float* __restrict__ bias) {
    // ring of 4 K-tiles: 4 * (256x32 A + 256x32 B) bf16 = 128 KiB
    __shared__ __align__(16) bf16 As[4][256 * 32];
    __shared__ __align__(16) bf16 Bs[4][256 * 32];

    constexpr int nt = K / 32;
    static_assert(nt >= 4 && (nt % 4) == 0, "K must be multiple of 128");

    const int tid = threadIdx.x;
    const int w = tid >> 6, lane = tid & 63;
    const int wm = w >> 2, wn = w & 3;          // 2 x 4 wave grid
    const int q = lane >> 4, m16 = lane & 15;

    // XCD-chunked remap of the 16x16 grid
    int bid = blockIdx.y * 16 + blockIdx.x;
    int xcd = bid & 7, inner = bid >> 3;
    int by = (xcd & 3) * 4 + (inner & 3);
    int bx = (xcd >> 2) * 8 + (inner >> 2);
    const int tm = by * 256, tn = bx * 256;

    // staging with pre-swizzled source chunk (LDS dest stays linear)
    const int srow = lane >> 2;            // 0..15
    const int scol = ((lane & 3) ^ ((lane >> 3) & 3)) * 8;
    const bf16* Ag = A + (tm + w * 32 + srow) * LDA + scol;
    const bf16* Bg = B + (tn + w * 32 + srow) * LDB + scol;

    v4f acc[8][4];
#pragma unroll
    for (int i = 0; i < 8; ++i)
#pragma unroll
        for (int j = 0; j < 4; ++j) acc[i][j] = (v4f){0.f, 0.f, 0.f, 0.f};

    // fragment read offsets with matching XOR on k-chunk
    const int sq = q ^ ((m16 >> 1) & 3);
    const int aoff = (wm * 128 + m16) * 32 + sq * 8;
    const int boff = (wn * 64 + m16) * 32 + sq * 8;

    // ---- prologue: stage K-tiles 0,1 into ring slots 0,1 (8 loads/wave) ----
#pragma unroll
    for (int t = 0; t < 2; ++t) {
        async16(&As[t][(w * 32) * 32],      Ag + t * 32);
        async16(&As[t][(w * 32 + 16) * 32], Ag + 16 * LDA + t * 32);
        async16(&Bs[t][(w * 32) * 32],      Bg + t * 32);
        async16(&Bs[t][(w * 32 + 16) * 32], Bg + 16 * LDB + t * 32);
    }
    asm volatile("s_waitcnt vmcnt(4)" ::: "memory");   // tile 0 landed; tile 1 in flight
    __builtin_amdgcn_s_barrier();
    __builtin_amdgcn_sched_barrier(0);

#pragma unroll 1
    for (int t4 = 0; t4 < nt; t4 += 4) {
#pragma unroll
        for (int tt = 0; tt < 4; ++tt) {
            const int t = t4 + tt;
            const int cur = tt;                 // ring slot being computed
            const int pre = (tt + 2) & 3;       // ring slot being staged (t+2)
            int kt = t + 2; if (kt >= nt) kt = 0;   // clamp: dead staging at tail
            const bf16* Asrc = Ag + kt * 32;
            const bf16* Bsrc = Bg + kt * 32;

            // ---------------- phase A: rows 0..63 of wave tile ----------------
            v8s af[4], bfr[4];
#pragma unroll
            for (int i = 0; i < 4; ++i)
                af[i] = *(const v8s*)&As[cur][aoff + i * 512];
#pragma unroll
            for (int j = 0; j < 4; ++j)
                bfr[j] = *(const v8s*)&Bs[cur][boff + j * 512];
            async16(&As[pre][(w * 32) * 32],      Asrc);
            async16(&As[pre][(w * 32 + 16) * 32], Asrc + 16 * LDA);
            __builtin_amdgcn_s_barrier();
            asm volatile("s_waitcnt lgkmcnt(0)" ::: "memory");
            __builtin_amdgcn_sched_barrier(0);
            __builtin_amdgcn_s_setprio(1);
#pragma unroll
            for (int i = 0; i < 4; ++i)
#pragma unroll
                for (int j = 0; j < 4; ++j)
                    acc[i][j] = __builtin_amdgcn_mfma_f32_16x16x32_bf16(af[i], bfr[j], acc[i][j], 0, 0, 0);
            __builtin_amdgcn_s_setprio(0);
            __builtin_amdgcn_sched_barrier(0);
            __builtin_amdgcn_s_barrier();
            __builtin_amdgcn_sched_barrier(0);

            // ---------------- phase B: rows 64..127 of wave tile ----------------
            v8s af2[4];
#pragma unroll
            for (int i = 0; i < 4; ++i)
                af2[i] = *(const v8s*)&As[cur][aoff + 2048 + i * 512];
            async16(&Bs[pre][(w * 32) * 32],      Bsrc);
            async16(&Bs[pre][(w * 32 + 16) * 32], Bsrc + 16 * LDB);
            __builtin_amdgcn_s_barrier();
            asm volatile("s_waitcnt lgkmcnt(0)" ::: "memory");
            __builtin_amdgcn_sched_barrier(0);
            __builtin_amdgcn_s_setprio(1);
#pragma unroll
            for (int i = 0; i < 4; ++i)
#pragma unroll
                for (int j = 0; j < 4; ++j)
                    acc[i + 4][j] = __builtin_amdgcn_mfma_f32_16x16x32_bf16(af2[i], bfr[j], acc[i + 4][j], 0, 0, 0);
            __builtin_amdgcn_s_setprio(0);
            // end of K-tile: tile t+1 landed; tile t+2's loads stay in flight.
            asm volatile("s_waitcnt vmcnt(4)" ::: "memory");
            __builtin_amdgcn_sched_barrier(0);
            __builtin_amdgcn_s_barrier();
            __builtin_amdgcn_sched_barrier(0);
        }
    }

    // epilogue: bias + gelu + bf16 store (i -> r -> j for write combining)
    float bc[4];
#pragma unroll
    for (int j = 0; j < 4; ++j)
        bc[j] = bias[tn + wn * 64 + 16 * j + m16];

#pragma unroll
    for (int i = 0; i < 8; ++i) {
#pragma unroll
        for (int r = 0; r < 4; ++r) {
            int row = tm + wm * 128 + 16 * i + q * 4 + r;
            int rowbase = row * LDC + tn + wn * 64 + m16;
#pragma unroll
            for (int j = 0; j < 4; ++j) {
                float v = acc[i][j][r] + bc[j];
                v = gelu_f(v);
                C[rowbase + 16 * j] = __float2bfloat16(v);
            }
        }
    }
}

// ---------------- attnV: out[b,s,h*64+c] = sum_k P[b,h,s,k] * VT[h*64+c, b*1024+k]
__global__ void __launch_bounds__(256) attnv_kernel(const float* __restrict__ P,
                                                    const bf16* __restrict__ VT,
                                                    bf16* __restrict__ out) {
    __shared__ __align__(16) bf16 As[128 * 32];
    __shared__ __align__(16) bf16 Bs[64 * 32];
    int z = blockIdx.z, b = z >> 4, h = z & 15;
    int tid = threadIdx.x, w = tid >> 6, lane = tid & 63;
    int q = lane >> 4, m16 = lane & 15;
    int srow = lane >> 2, scol = (lane & 3) * 8;

    const float* Ab = P + z * 1048576 + (blockIdx.y * 128 + (tid >> 1)) * 1024 + (tid & 1) * 16;
    const bf16* Bb = VT + (h * 64 + w * 16 + srow) * 4096 + b * 1024 + scol;
    uint4* asd = (uint4*)&As[(tid >> 1) * 32 + (tid & 1) * 16];
    bf16* bsw = &Bs[(w * 16) * 32];

    v4f acc[2][4];
#pragma unroll
    for (int i = 0; i < 2; ++i)
#pragma unroll
        for (int j = 0; j < 4; ++j) acc[i][j] = (v4f){0.f, 0.f, 0.f, 0.f};

#pragma unroll 1
    for (int k0 = 0; k0 < 1024; k0 += 32) {
        const float4* s4 = (const float4*)(Ab + k0);
        float4 f0 = s4[0], f1 = s4[1], f2 = s4[2], f3 = s4[3];
        async16(bsw, Bb + k0);
        uint4 u0, u1;
        u0.x = pk2(f0.x, f0.y); u0.y = pk2(f0.z, f0.w);
        u0.z = pk2(f1.x, f1.y); u0.w = pk2(f1.z, f1.w);
        u1.x = pk2(f2.x, f2.y); u1.y = pk2(f2.z, f2.w);
        u1.z = pk2(f3.x, f3.y); u1.w = pk2(f3.z, f3.w);
        asd[0] = u0; asd[1] = u1;
        __syncthreads();
        v8s af[2], bfr[4];
        af[0] = *(const v8s*)&As[(w * 32 + m16) * 32 + q * 8];
        af[1] = *(const v8s*)&As[(w * 32 + 16 + m16) * 32 + q * 8];
#pragma unroll
        for (int j = 0; j < 4; ++j)
            bfr[j] = *(const v8s*)&Bs[(16 * j + m16) * 32 + q * 8];
#pragma unroll
        for (int i = 0; i < 2; ++i)
#pragma unroll
            for (int j = 0; j < 4; ++j)
                acc[i][j] = __builtin_amdgcn_mfma_f32_16x16x32_bf16(af[i], bfr[j], acc[i][j], 0, 0, 0);
        __syncthreads();
    }

    int orow0 = b * 1024 + blockIdx.y * 128 + w * 32;
#pragma unroll
    for (int i = 0; i < 2; ++i)
#pragma unroll
        for (int r = 0; r < 4; ++r) {
            int row = orow0 + 16 * i + q * 4 + r;
#pragma unroll
            for (int j = 0; j < 4; ++j) {
                int col = h * 64 + 16 * j + m16;
                out[row * 1024 + col] = __float2bfloat16(acc[i][j][r]);
            }
        }
}

// ---------------- host ----------------
extern "C" void kernel_launch(void* const* d_in, const int* in_sizes, int n_in,
                              void* d_out, int out_size, void* d_ws, size_t ws_size,
                              hipStream_t stream) {
    (void)in_sizes; (void)n_in; (void)out_size; (void)ws_size;
    const float* x  = (const float*)d_in[0];
    const float* Wq = (const float*)d_in[1];
    const float* bq = (const float*)d_in[2];
    const float* Wk = (const float*)d_in[3];
    const float* bk = (const float*)d_in[4];
    const float* Wv = (const float*)d_in[5];
    const float* bv = (const float*)d_in[6];
    const float* Wo = (const float*)d_in[7];
    const float* bo = (const float*)d_in[8];
    const float* W1 = (const float*)d_in[9];
    const float* b1 = (const float*)d_in[10];
    const float* Wm = (const float*)d_in[11];
    const float* bm = (const float*)d_in[12];
    const float* W2 = (const float*)d_in[13];
    const float* b2 = (const float*)d_in[14];
    const float* g1 = (const float*)d_in[15];
    const float* be1 = (const float*)d_in[16];
    const float* g2 = (const float*)d_in[17];
    const float* be2 = (const float*)d_in[18];

    char* ws = (char*)d_ws;
    const size_t MB = 1024 * 1024;
    bf16* WQb = (bf16*)(ws + 0 * MB);
    bf16* WKb = (bf16*)(ws + 2 * MB);
    bf16* WVb = (bf16*)(ws + 4 * MB);
    bf16* WOb = (bf16*)(ws + 6 * MB);
    bf16* W1b = (bf16*)(ws + 8 * MB);
    bf16* WMb = (bf16*)(ws + 16 * MB);
    bf16* W2b = (bf16*)(ws + 48 * MB);
    bf16* HB  = (bf16*)(ws + 56 * MB);
    bf16* QB  = (bf16*)(ws + 64 * MB);
    bf16* KB  = (bf16*)(ws + 72 * MB);
    bf16* VT  = (bf16*)(ws + 80 * MB);
    bf16* AT  = (bf16*)(ws + 88 * MB);
    float* X1 = (float*)(ws + 96 * MB);
    bf16* F1  = (bf16*)(ws + 112 * MB);
    bf16* F2  = (bf16*)(ws + 144 * MB);
    // bf16 scores scratch (128 MB): lives 96..224 MB. Overlaps X1/F1/F2, which are
    // only written AFTER topk consumed SCb (Wo-gemm onward) -> no conflict.
    bf16* SCb = (bf16*)(ws + 96 * MB);

    float* out_x  = (float*)d_out;
    float* scores = out_x + 4194304;

    F2BP fp;
    fp.src[0] = Wq; fp.dst[0] = WQb; fp.n4[0] = 262144;
    fp.src[1] = Wk; fp.dst[1] = WKb; fp.n4[1] = 262144;
    fp.src[2] = Wv; fp.dst[2] = WVb; fp.n4[2] = 262144;
    fp.src[3] = Wo; fp.dst[3] = WOb; fp.n4[3] = 262144;
    fp.src[4] = W1; fp.dst[4] = W1b; fp.n4[4] = 1048576;
    fp.src[5] = Wm; fp.dst[5] = WMb; fp.n4[5] = 4194304;
    fp.src[6] = W2; fp.dst[6] = W2b; fp.n4[6] = 1048576;
    hipLaunchKernelGGL(f2b_multi, dim3(1024, 7), dim3(256), 0, stream, fp);

    hipLaunchKernelGGL(ln_kernel, dim3(4096), dim3(256), 0, stream, x, g1, be1, HB);

    gemm_t<1024,1024,1024,1024,1024,1,0,0><<<dim3(8,32,1), 256, 0, stream>>>(
        HB, WQb, nullptr, QB, bq, nullptr, 1.f);
    gemm_t<1024,1024,1024,1024,1024,1,0,0><<<dim3(8,32,1), 256, 0, stream>>>(
        HB, WKb, nullptr, KB, bk, nullptr, 1.f);
    gemm_t<1024,1024,1024,4096,4096,2,0,0><<<dim3(32,8,1), 256, 0, stream>>>(
        WVb, HB, nullptr, VT, bv, nullptr, 1.f);

    // QK^T -> bf16 scores (halves score write + topk read traffic)
    gemm_t<64,1024,1024,1024,1024,0,0,1><<<dim3(8,8,64), 256, 0, stream>>>(
        QB, KB, nullptr, SCb, nullptr, nullptr, 0.125f);

    hipLaunchKernelGGL(topk_softmax, dim3(16384), dim3(256), 0, stream,
                       (const unsigned short*)SCb, scores);

    hipLaunchKernelGGL(attnv_kernel, dim3(1,8,64), dim3(256), 0, stream, scores, VT, AT);

    gemm_t<1024,1024,1024,1024,1024,1,0,0><<<dim3(8,32,1), 256, 0, stream>>>(
        AT, WOb, X1, nullptr, bo, x, 1.f);

    hipLaunchKernelGGL(ln_kernel, dim3(4096), dim3(256), 0, stream, X1, g2, be2, HB);

    // FFN: deep-pipelined 256^2 kernels for the two 4096x4096-output GEMMs
    gemm256<1024,1024,1024,4096><<<dim3(16,16,1), 512, 0, stream>>>(HB, W1b, F1, b1);
    gemm256<4096,4096,4096,4096><<<dim3(16,16,1), 512, 0, stream>>>(F1, WMb, F2, bm);

    gemm_t<4096,4096,4096,1024,1024,1,0,0><<<dim3(8,32,1), 256, 0, stream>>>(
        F2, W2b, out_x, nullptr, b2, X1, 1.f);
}

// Round 4
// 914.117 us; speedup vs baseline: 1.3353x; 1.1569x over previous
//
#include <hip/hip_runtime.h>
#include <hip/hip_bf16.h>

typedef __hip_bfloat16 bf16;
typedef float v4f __attribute__((ext_vector_type(4)));
typedef short v8s __attribute__((ext_vector_type(8)));

#define KSEL 307

__device__ static inline void async16(bf16* lds, const bf16* g) {
    __builtin_amdgcn_global_load_lds(
        (const __attribute__((address_space(1))) void*)g,
        (__attribute__((address_space(3))) void*)lds, 16, 0, 0);
}

__device__ static inline unsigned short f2bu(float f) {
    __hip_bfloat16 h = __float2bfloat16(f);
    return *reinterpret_cast<unsigned short*>(&h);
}

__device__ static inline unsigned pk2(float a, float b) {
    __hip_bfloat162 h = __float22bfloat162_rn(make_float2(a, b));
    return *reinterpret_cast<unsigned*>(&h);
}

// tanh-approx gelu via hardware exp: ~8 VALU ops vs ~35 for erff.
__device__ static inline float gelu_f(float v) {
    float c = v * fmaf(v * v, 0.0356774081f, 0.7978845608f);
    return v / (1.0f + __expf(-2.0f * c));
}

// ---------------- fp32 -> bf16 convert, 7 segments in one launch ----------------
struct F2BP { const float* src[7]; bf16* dst[7]; int n4[7]; };

__global__ void __launch_bounds__(256) f2b_multi(F2BP p) {
    int s = blockIdx.y;
    const float* __restrict__ in = p.src[s];
    bf16* __restrict__ out = p.dst[s];
    int n4 = p.n4[s];
    for (int i = blockIdx.x * 256 + threadIdx.x; i < n4; i += gridDim.x * 256) {
        float4 v = ((const float4*)in)[i];
        ushort4 u = make_ushort4(f2bu(v.x), f2bu(v.y), f2bu(v.z), f2bu(v.w));
        ((ushort4*)out)[i] = u;
    }
}

// ---------------- LayerNorm (row of 1024) ----------------
__global__ void __launch_bounds__(256) ln_kernel(const float* __restrict__ x,
                                                 const float* __restrict__ g,
                                                 const float* __restrict__ be,
                                                 bf16* __restrict__ out) {
    int row = blockIdx.x;
    int tid = threadIdx.x;
    const float* xr = x + row * 1024;
    float4 v = ((const float4*)xr)[tid];
    float s = v.x + v.y + v.z + v.w;
    float s2 = v.x*v.x + v.y*v.y + v.z*v.z + v.w*v.w;
    for (int off = 32; off > 0; off >>= 1) {
        s  += __shfl_down(s, off);
        s2 += __shfl_down(s2, off);
    }
    __shared__ float sh[4], sh2[4];
    int w = tid >> 6;
    if ((tid & 63) == 0) { sh[w] = s; sh2[w] = s2; }
    __syncthreads();
    float mean = (sh[0]+sh[1]+sh[2]+sh[3]) * (1.0f / 1024.f);
    float ms   = (sh2[0]+sh2[1]+sh2[2]+sh2[3]) * (1.0f / 1024.f);
    float var  = ms - mean*mean;
    float rs   = rsqrtf(var + 1e-5f);
    float4 gg = ((const float4*)g)[tid];
    float4 bb = ((const float4*)be)[tid];
    ushort4 o = make_ushort4(
        f2bu((v.x-mean)*rs*gg.x + bb.x),
        f2bu((v.y-mean)*rs*gg.y + bb.y),
        f2bu((v.z-mean)*rs*gg.z + bb.z),
        f2bu((v.w-mean)*rs*gg.w + bb.w));
    ((ushort4*)out)[row * 256 + tid] = o;
}

// ---------------- top-k threshold + masked softmax, ONE ROW PER WAVE ----------
// Input: bf16 scores. Outputs: fp32 probs (mandatory) + bf16 probs written
// in place over the score buffer (consumed by attnv with direct LDS staging).
__global__ void __launch_bounds__(256) topk_softmax(unsigned short* __restrict__ scb,
                                                    float* __restrict__ out) {
    __shared__ int hist[4][256];
    const int tid = threadIdx.x;
    const int wid = tid >> 6, lane = tid & 63;
    const long long row = (long long)blockIdx.x * 4 + wid;
    unsigned short* pb = scb + row * 1024;
    float* po = out + row * 1024;
    int* h = hist[wid];

    unsigned short raw[16];
    unsigned key[16];
    float v[16];
#pragma unroll
    for (int j = 0; j < 4; ++j) {
        ushort4 t = *(const ushort4*)(pb + lane * 4 + j * 256);
        raw[j*4+0] = t.x; raw[j*4+1] = t.y; raw[j*4+2] = t.z; raw[j*4+3] = t.w;
    }
#pragma unroll
    for (int j = 0; j < 16; ++j) {
        unsigned u = raw[j];
        key[j] = (u & 0x8000u) ? (0xFFFFu & ~u) : (u | 0x8000u);
        v[j] = __uint_as_float(u << 16);            // exact bf16 -> f32
    }

    unsigned prefix = 0;
    int need = KSEL;
#pragma unroll
    for (int pass = 0; pass < 2; ++pass) {
        const int shift = 8 - 8 * pass;
        *(int4*)&h[lane * 4] = make_int4(0, 0, 0, 0);
        asm volatile("s_waitcnt lgkmcnt(0)" ::: "memory");
#pragma unroll
        for (int j = 0; j < 16; ++j) {
            bool cand = (pass == 0) || ((key[j] >> 8) == prefix);
            if (cand) atomicAdd(&h[(key[j] >> shift) & 255], 1);
        }
        asm volatile("s_waitcnt lgkmcnt(0)" ::: "memory");
        int4 hc = *(const int4*)&h[lane * 4];
        int s_local = hc.x + hc.y + hc.z + hc.w;
        int sfx = s_local;
#pragma unroll
        for (int off = 1; off < 64; off <<= 1) {
            int o = __shfl_down(sfx, off);
            if (lane + off < 64) sfx += o;
        }
        int sfx_next = __shfl_down(sfx, 1);
        if (lane == 63) sfx_next = 0;
        int above_lane = sfx - s_local;
        int suf3 = above_lane + hc.w;
        int suf2 = suf3 + hc.z;
        int suf1 = suf2 + hc.y;
        int suf0 = suf1 + hc.x;
        int bloc = -1, abv = 0;
        if (suf0 >= need && suf1 < need)     { bloc = lane*4+0; abv = suf1; }
        if (suf1 >= need && suf2 < need)     { bloc = lane*4+1; abv = suf2; }
        if (suf2 >= need && suf3 < need)     { bloc = lane*4+2; abv = suf3; }
        if (suf3 >= need && sfx_next < need) { bloc = lane*4+3; abv = sfx_next; }
        unsigned long long mask = __ballot(bloc >= 0);
        int src = __ffsll((unsigned long long)mask) - 1;
        int b = __shfl(bloc, src);
        int above = __shfl(abv, src);
        prefix = (prefix << 8) | (unsigned)b;
        need -= above;
    }

    float mx = v[0];
#pragma unroll
    for (int j = 1; j < 16; ++j) mx = fmaxf(mx, v[j]);
#pragma unroll
    for (int off = 32; off > 0; off >>= 1) mx = fmaxf(mx, __shfl_xor(mx, off));
    float sum = 0.f;
#pragma unroll
    for (int j = 0; j < 16; ++j) {
        bool sel = key[j] >= prefix;
        v[j] = sel ? __expf(v[j] - mx) : 0.f;
        sum += v[j];
    }
#pragma unroll
    for (int off = 32; off > 0; off >>= 1) sum += __shfl_xor(sum, off);
    float inv = 1.0f / sum;
#pragma unroll
    for (int j = 0; j < 4; ++j) {
        float4 o;
        o.x = v[j*4+0]*inv; o.y = v[j*4+1]*inv; o.z = v[j*4+2]*inv; o.w = v[j*4+3]*inv;
        *(float4*)(po + lane * 4 + j * 256) = o;
        uint2 u;                                    // bf16 copy for attnv
        u.x = pk2(o.x, o.y); u.y = pk2(o.z, o.w);
        *(uint2*)(pb + lane * 4 + j * 256) = u;
    }
}

// ---------------- gemm_t (128x128, 2-barrier): kept ONLY for QK^T (K=64) ----
template<int K, int LDA, int LDB, int LDC, int N, int BMODE, int ACT, int BM>
__global__ void __launch_bounds__(256) gemm_t(const bf16* __restrict__ A,
                                              const bf16* __restrict__ B,
                                              float* __restrict__ Cf,
                                              bf16* __restrict__ Cb,
                                              const float* __restrict__ bias,
                                              const float* __restrict__ resid,
                                              float scale) {
    __shared__ __align__(16) bf16 As[128 * 32];
    __shared__ __align__(16) bf16 Bs[128 * 32];
    int offA = 0, offB = 0, offC = 0;
    if (BM == 1) {
        int z = blockIdx.z;
        int b = z >> 4, h = z & 15;
        offA = b * 1048576 + h * 64;
        offB = offA;
        offC = z * 1048576;
    }
    const int tid = threadIdx.x;
    const int w = tid >> 6, lane = tid & 63;
    const int tm = blockIdx.y * 128, tn = blockIdx.x * 128;
    const int q = lane >> 4, m16 = lane & 15;
    const int r0 = (w >> 1) * 64, c0 = (w & 1) * 64;
    const int srow = lane >> 2;
    const int scol = ((lane & 3) ^ ((lane >> 3) & 3)) * 8;
    const int sq = q ^ ((m16 >> 1) & 3);

    v4f acc[4][4];
#pragma unroll
    for (int i = 0; i < 4; ++i)
#pragma unroll
        for (int j = 0; j < 4; ++j) acc[i][j] = (v4f){0.f, 0.f, 0.f, 0.f};

    const bf16* Ab = A + offA + (tm + w * 16 + srow) * LDA + scol;
    const bf16* Bb = B + offB + (tn + w * 16 + srow) * LDB + scol;
    bf16* Asw = &As[(w * 16) * 32];
    bf16* Bsw = &Bs[(w * 16) * 32];

#pragma unroll 1
    for (int k0 = 0; k0 < K; k0 += 32) {
        async16(Asw,           Ab + k0);
        async16(Asw + 64 * 32, Ab + 64 * LDA + k0);
        async16(Bsw,           Bb + k0);
        async16(Bsw + 64 * 32, Bb + 64 * LDB + k0);
        __syncthreads();
        v8s af[4], bfr[4];
#pragma unroll
        for (int i = 0; i < 4; ++i)
            af[i] = *(const v8s*)&As[(r0 + 16 * i + m16) * 32 + sq * 8];
#pragma unroll
        for (int j = 0; j < 4; ++j)
            bfr[j] = *(const v8s*)&Bs[(c0 + 16 * j + m16) * 32 + sq * 8];
#pragma unroll
        for (int i = 0; i < 4; ++i)
#pragma unroll
            for (int j = 0; j < 4; ++j)
                acc[i][j] = __builtin_amdgcn_mfma_f32_16x16x32_bf16(af[i], bfr[j], acc[i][j], 0, 0, 0);
        __syncthreads();
    }

    float bc[4];
#pragma unroll
    for (int j = 0; j < 4; ++j)
        bc[j] = (BMODE == 1) ? bias[tn + c0 + 16 * j + m16] : 0.f;

#pragma unroll
    for (int i = 0; i < 4; ++i) {
#pragma unroll
        for (int r = 0; r < 4; ++r) {
            int row = tm + r0 + 16 * i + q * 4 + r;
            float br = (BMODE == 2) ? bias[row] : 0.f;
            int rowbase = offC + row * LDC + tn + c0 + m16;
#pragma unroll
            for (int j = 0; j < 4; ++j) {
                float v = acc[i][j][r] * scale + bc[j] + br;
                if (ACT) v = gelu_f(v);
                int idx = rowbase + 16 * j;
                if (resid) v += resid[idx];
                if (Cf) Cf[idx] = v;
                if (Cb) Cb[idx] = __float2bfloat16(v);
            }
        }
    }
}

// ---------------- gemm128p: 128x128, 8 waves (64x32 each), 4-deep LDS ring,
// counted vmcnt(2), ONE barrier per K-tile, T2 source-swizzle.
// Used for QKV, VT, Wo, W2 (K >= 1024).
template<int K, int LDA, int LDB, int LDC, int BMODE>
__global__ void __launch_bounds__(512, 2) gemm128p(const bf16* __restrict__ A,
                                                   const bf16* __restrict__ B,
                                                   float* __restrict__ Cf,
                                                   bf16* __restrict__ Cb,
                                                   const float* __restrict__ bias,
                                                   const float* __restrict__ resid) {
    __shared__ __align__(16) bf16 As[4][128 * 32];   // 4 ring slots, 64 KiB total
    __shared__ __align__(16) bf16 Bs[4][128 * 32];

    constexpr int nt = K / 32;
    static_assert(nt >= 4, "K >= 128");

    const int tid = threadIdx.x;
    const int w = tid >> 6, lane = tid & 63;
    const int wr = w >> 2, wc = w & 3;          // 2 x 4 wave grid: 64 x 32 per wave
    const int q = lane >> 4, m16 = lane & 15;
    const int tm = blockIdx.y * 128, tn = blockIdx.x * 128;

    // staging: 512 threads cover 128 rows x 32 cols (16B/thread), source-swizzled
    const int srow = lane >> 2;
    const int scol = ((lane & 3) ^ ((lane >> 3) & 3)) * 8;
    const bf16* Ag = A + (tm + w * 16 + srow) * LDA + scol;
    const bf16* Bg = B + (tn + w * 16 + srow) * LDB + scol;

    v4f acc[4][2];
#pragma unroll
    for (int i = 0; i < 4; ++i)
#pragma unroll
        for (int j = 0; j < 2; ++j) acc[i][j] = (v4f){0.f, 0.f, 0.f, 0.f};

    const int sq = q ^ ((m16 >> 1) & 3);
    const int aoff = (wr * 64 + m16) * 32 + sq * 8;
    const int boff = (wc * 32 + m16) * 32 + sq * 8;

    // prologue: stage tiles 0,1 (2 loads/thread each)
#pragma unroll
    for (int t = 0; t < 2; ++t) {
        async16(&As[t][(w * 16) * 32], Ag + t * 32);
        async16(&Bs[t][(w * 16) * 32], Bg + t * 32);
    }
    asm volatile("s_waitcnt vmcnt(2)" ::: "memory");   // tile 0 landed
    __builtin_amdgcn_s_barrier();
    __builtin_amdgcn_sched_barrier(0);

#pragma unroll 1
    for (int t = 0; t < nt; ++t) {
        const int cur = t & 3, pre = (t + 2) & 3;
        const int kt = (t + 2 < nt) ? (t + 2) : 0;   // tail: dead staging
        v8s af[4], bfr[2];
#pragma unroll
        for (int i = 0; i < 4; ++i)
            af[i] = *(const v8s*)&As[cur][aoff + i * 512];
#pragma unroll
        for (int j = 0; j < 2; ++j)
            bfr[j] = *(const v8s*)&Bs[cur][boff + j * 512];
        async16(&As[pre][(w * 16) * 32], Ag + kt * 32);
        async16(&Bs[pre][(w * 16) * 32], Bg + kt * 32);
        asm volatile("s_waitcnt lgkmcnt(0)" ::: "memory");
        __builtin_amdgcn_sched_barrier(0);
        __builtin_amdgcn_s_setprio(1);
#pragma unroll
        for (int i = 0; i < 4; ++i)
#pragma unroll
            for (int j = 0; j < 2; ++j)
                acc[i][j] = __builtin_amdgcn_mfma_f32_16x16x32_bf16(af[i], bfr[j], acc[i][j], 0, 0, 0);
        __builtin_amdgcn_s_setprio(0);
        __builtin_amdgcn_sched_barrier(0);
        // tile t+1 landed (its 2 loads are oldest); t+2's stay in flight
        asm volatile("s_waitcnt vmcnt(2)" ::: "memory");
        __builtin_amdgcn_sched_barrier(0);
        __builtin_amdgcn_s_barrier();
        __builtin_amdgcn_sched_barrier(0);
    }
    asm volatile("s_waitcnt vmcnt(0)" ::: "memory");   // drain dead tail loads

    float bc[2];
#pragma unroll
    for (int j = 0; j < 2; ++j)
        bc[j] = (BMODE == 1) ? bias[tn + wc * 32 + 16 * j + m16] : 0.f;

#pragma unroll
    for (int i = 0; i < 4; ++i) {
#pragma unroll
        for (int r = 0; r < 4; ++r) {
            int row = tm + wr * 64 + 16 * i + q * 4 + r;
            float br = (BMODE == 2) ? bias[row] : 0.f;
            int rowbase = row * LDC + tn + wc * 32 + m16;
#pragma unroll
            for (int j = 0; j < 2; ++j) {
                float v = acc[i][j][r] + bc[j] + br;
                int idx = rowbase + 16 * j;
                if (resid) v += resid[idx];
                if (Cf) Cf[idx] = v;
                if (Cb) Cb[idx] = __float2bfloat16(v);
            }
        }
    }
}

// ---------------- 256x256 deep-pipelined GEMM (W1, Wm) — unchanged ----------
template<int K, int LDA, int LDB, int LDC>
__global__ void __launch_bounds__(512, 2) gemm256(const bf16* __restrict__ A,
                                                  const bf16* __restrict__ B,
                                                  bf16* __restrict__ C,
                                                  const float* __restrict__ bias) {
    __shared__ __align__(16) bf16 As[4][256 * 32];
    __shared__ __align__(16) bf16 Bs[4][256 * 32];

    constexpr int nt = K / 32;
    static_assert(nt >= 4 && (nt % 4) == 0, "K must be multiple of 128");

    const int tid = threadIdx.x;
    const int w = tid >> 6, lane = tid & 63;
    const int wm = w >> 2, wn = w & 3;
    const int q = lane >> 4, m16 = lane & 15;

    int bid = blockIdx.y * 16 + blockIdx.x;
    int xcd = bid & 7, inner = bid >> 3;
    int by = (xcd & 3) * 4 + (inner & 3);
    int bx = (xcd >> 2) * 8 + (inner >> 2);
    const int tm = by * 256, tn = bx * 256;

    const int srow = lane >> 2;
    const int scol = ((lane & 3) ^ ((lane >> 3) & 3)) * 8;
    const bf16* Ag = A + (tm + w * 32 + srow) * LDA + scol;
    const bf16* Bg = B + (tn + w * 32 + srow) * LDB + scol;

    v4f acc[8][4];
#pragma unroll
    for (int i = 0; i < 8; ++i)
#pragma unroll
        for (int j = 0; j < 4; ++j) acc[i][j] = (v4f){0.f, 0.f, 0.f, 0.f};

    const int sq = q ^ ((m16 >> 1) & 3);
    const int aoff = (wm * 128 + m16) * 32 + sq * 8;
    const int boff = (wn * 64 + m16) * 32 + sq * 8;

#pragma unroll
    for (int t = 0; t < 2; ++t) {
        async16(&As[t][(w * 32) * 32],      Ag + t * 32);
        async16(&As[t][(w * 32 + 16) * 32], Ag + 16 * LDA + t * 32);
        async16(&Bs[t][(w * 32) * 32],      Bg + t * 32);
        async16(&Bs[t][(w * 32 + 16) * 32], Bg + 16 * LDB + t * 32);
    }
    asm volatile("s_waitcnt vmcnt(4)" ::: "memory");
    __builtin_amdgcn_s_barrier();
    __builtin_amdgcn_sched_barrier(0);

#pragma unroll 1
    for (int t4 = 0; t4 < nt; t4 += 4) {
#pragma unroll
        for (int tt = 0; tt < 4; ++tt) {
            const int t = t4 + tt;
            const int cur = tt;
            const int pre = (tt + 2) & 3;
            int kt = t + 2; if (kt >= nt) kt = 0;
            const bf16* Asrc = Ag + kt * 32;
            const bf16* Bsrc = Bg + kt * 32;

            v8s af[4], bfr[4];
#pragma unroll
            for (int i = 0; i < 4; ++i)
                af[i] = *(const v8s*)&As[cur][aoff + i * 512];
#pragma unroll
            for (int j = 0; j < 4; ++j)
                bfr[j] = *(const v8s*)&Bs[cur][boff + j * 512];
            async16(&As[pre][(w * 32) * 32],      Asrc);
            async16(&As[pre][(w * 32 + 16) * 32], Asrc + 16 * LDA);
            __builtin_amdgcn_s_barrier();
            asm volatile("s_waitcnt lgkmcnt(0)" ::: "memory");
            __builtin_amdgcn_sched_barrier(0);
            __builtin_amdgcn_s_setprio(1);
#pragma unroll
            for (int i = 0; i < 4; ++i)
#pragma unroll
                for (int j = 0; j < 4; ++j)
                    acc[i][j] = __builtin_amdgcn_mfma_f32_16x16x32_bf16(af[i], bfr[j], acc[i][j], 0, 0, 0);
            __builtin_amdgcn_s_setprio(0);
            __builtin_amdgcn_sched_barrier(0);
            __builtin_amdgcn_s_barrier();
            __builtin_amdgcn_sched_barrier(0);

            v8s af2[4];
#pragma unroll
            for (int i = 0; i < 4; ++i)
                af2[i] = *(const v8s*)&As[cur][aoff + 2048 + i * 512];
            async16(&Bs[pre][(w * 32) * 32],      Bsrc);
            async16(&Bs[pre][(w * 32 + 16) * 32], Bsrc + 16 * LDB);
            __builtin_amdgcn_s_barrier();
            asm volatile("s_waitcnt lgkmcnt(0)" ::: "memory");
            __builtin_amdgcn_sched_barrier(0);
            __builtin_amdgcn_s_setprio(1);
#pragma unroll
            for (int i = 0; i < 4; ++i)
#pragma unroll
                for (int j = 0; j < 4; ++j)
                    acc[i + 4][j] = __builtin_amdgcn_mfma_f32_16x16x32_bf16(af2[i], bfr[j], acc[i + 4][j], 0, 0, 0);
            __builtin_amdgcn_s_setprio(0);
            asm volatile("s_waitcnt vmcnt(4)" ::: "memory");
            __builtin_amdgcn_sched_barrier(0);
            __builtin_amdgcn_s_barrier();
            __builtin_amdgcn_sched_barrier(0);
        }
    }

    float bc[4];
#pragma unroll
    for (int j = 0; j < 4; ++j)
        bc[j] = bias[tn + wn * 64 + 16 * j + m16];

#pragma unroll
    for (int i = 0; i < 8; ++i) {
#pragma unroll
        for (int r = 0; r < 4; ++r) {
            int row = tm + wm * 128 + 16 * i + q * 4 + r;
            int rowbase = row * LDC + tn + wn * 64 + m16;
#pragma unroll
            for (int j = 0; j < 4; ++j) {
                float v = acc[i][j][r] + bc[j];
                v = gelu_f(v);
                C[rowbase + 16 * j] = __float2bfloat16(v);
            }
        }
    }
}

// ---------------- attnV (bf16 P): out[b,s,h*64+c] = sum_k P[z,s,k] * VT[h*64+c,b*1024+k]
// 4-deep ring, counted vmcnt(3), one barrier per K-tile, direct LDS staging.
__global__ void __launch_bounds__(256) attnv_kernel(const bf16* __restrict__ P,
                                                    const bf16* __restrict__ VT,
                                                    bf16* __restrict__ out) {
    __shared__ __align__(16) bf16 As[4][128 * 32];   // 32 KiB
    __shared__ __align__(16) bf16 Bs[4][64 * 32];    // 16 KiB
    int z = blockIdx.z, b = z >> 4, h = z & 15;
    int tid = threadIdx.x, w = tid >> 6, lane = tid & 63;
    int q = lane >> 4, m16 = lane & 15;
    int srow = lane >> 2;
    int scol = ((lane & 3) ^ ((lane >> 3) & 3)) * 8;
    const int sq = q ^ ((m16 >> 1) & 3);

    const bf16* Ab = P + z * 1048576 + (blockIdx.y * 128 + w * 16 + srow) * 1024 + scol;
    const bf16* Bb = VT + (h * 64 + w * 16 + srow) * 4096 + b * 1024 + scol;

    v4f acc[2][4];
#pragma unroll
    for (int i = 0; i < 2; ++i)
#pragma unroll
        for (int j = 0; j < 4; ++j) acc[i][j] = (v4f){0.f, 0.f, 0.f, 0.f};

    const int aoff = (w * 32 + m16) * 32 + sq * 8;
    const int boff = (m16) * 32 + sq * 8;

    // prologue: stage tiles 0,1 (3 loads/thread each)
#pragma unroll
    for (int t = 0; t < 2; ++t) {
        async16(&As[t][(w * 16) * 32],        Ab + t * 32);
        async16(&As[t][(64 + w * 16) * 32],   Ab + 64 * 1024 + t * 32);
        async16(&Bs[t][(w * 16) * 32],        Bb + t * 32);
    }
    asm volatile("s_waitcnt vmcnt(3)" ::: "memory");   // tile 0 landed
    __builtin_amdgcn_s_barrier();
    __builtin_amdgcn_sched_barrier(0);

#pragma unroll 1
    for (int t = 0; t < 32; ++t) {
        const int cur = t & 3, pre = (t + 2) & 3;
        const int kt = (t + 2 < 32) ? (t + 2) : 0;
        v8s af[2], bfr[4];
        af[0] = *(const v8s*)&As[cur][aoff];
        af[1] = *(const v8s*)&As[cur][aoff + 512];
#pragma unroll
        for (int j = 0; j < 4; ++j)
            bfr[j] = *(const v8s*)&Bs[cur][boff + j * 512];
        async16(&As[pre][(w * 16) * 32],      Ab + kt * 32);
        async16(&As[pre][(64 + w * 16) * 32], Ab + 64 * 1024 + kt * 32);
        async16(&Bs[pre][(w * 16) * 32],      Bb + kt * 32);
        asm volatile("s_waitcnt lgkmcnt(0)" ::: "memory");
        __builtin_amdgcn_sched_barrier(0);
        __builtin_amdgcn_s_setprio(1);
#pragma unroll
        for (int i = 0; i < 2; ++i)
#pragma unroll
            for (int j = 0; j < 4; ++j)
                acc[i][j] = __builtin_amdgcn_mfma_f32_16x16x32_bf16(af[i], bfr[j], acc[i][j], 0, 0, 0);
        __builtin_amdgcn_s_setprio(0);
        __builtin_amdgcn_sched_barrier(0);
        asm volatile("s_waitcnt vmcnt(3)" ::: "memory");
        __builtin_amdgcn_sched_barrier(0);
        __builtin_amdgcn_s_barrier();
        __builtin_amdgcn_sched_barrier(0);
    }
    asm volatile("s_waitcnt vmcnt(0)" ::: "memory");   // drain dead tail loads

    int orow0 = b * 1024 + blockIdx.y * 128 + w * 32;
#pragma unroll
    for (int i = 0; i < 2; ++i)
#pragma unroll
        for (int r = 0; r < 4; ++r) {
            int row = orow0 + 16 * i + q * 4 + r;
#pragma unroll
            for (int j = 0; j < 4; ++j) {
                int col = h * 64 + 16 * j + m16;
                out[row * 1024 + col] = __float2bfloat16(acc[i][j][r]);
            }
        }
}

// ---------------- host ----------------
extern "C" void kernel_launch(void* const* d_in, const int* in_sizes, int n_in,
                              void* d_out, int out_size, void* d_ws, size_t ws_size,
                              hipStream_t stream) {
    (void)in_sizes; (void)n_in; (void)out_size; (void)ws_size;
    const float* x  = (const float*)d_in[0];
    const float* Wq = (const float*)d_in[1];
    const float* bq = (const float*)d_in[2];
    const float* Wk = (const float*)d_in[3];
    const float* bk = (const float*)d_in[4];
    const float* Wv = (const float*)d_in[5];
    const float* bv = (const float*)d_in[6];
    const float* Wo = (const float*)d_in[7];
    const float* bo = (const float*)d_in[8];
    const float* W1 = (const float*)d_in[9];
    const float* b1 = (const float*)d_in[10];
    const float* Wm = (const float*)d_in[11];
    const float* bm = (const float*)d_in[12];
    const float* W2 = (const float*)d_in[13];
    const float* b2 = (const float*)d_in[14];
    const float* g1 = (const float*)d_in[15];
    const float* be1 = (const float*)d_in[16];
    const float* g2 = (const float*)d_in[17];
    const float* be2 = (const float*)d_in[18];

    char* ws = (char*)d_ws;
    const size_t MB = 1024 * 1024;
    bf16* WQb = (bf16*)(ws + 0 * MB);
    bf16* WKb = (bf16*)(ws + 2 * MB);
    bf16* WVb = (bf16*)(ws + 4 * MB);
    bf16* WOb = (bf16*)(ws + 6 * MB);
    bf16* W1b = (bf16*)(ws + 8 * MB);
    bf16* WMb = (bf16*)(ws + 16 * MB);
    bf16* W2b = (bf16*)(ws + 48 * MB);
    bf16* HB  = (bf16*)(ws + 56 * MB);
    bf16* QB  = (bf16*)(ws + 64 * MB);
    bf16* KB  = (bf16*)(ws + 72 * MB);
    bf16* VT  = (bf16*)(ws + 80 * MB);
    bf16* AT  = (bf16*)(ws + 88 * MB);
    float* X1 = (float*)(ws + 96 * MB);
    bf16* F1  = (bf16*)(ws + 112 * MB);
    bf16* F2  = (bf16*)(ws + 144 * MB);
    // bf16 scores/probs scratch (128 MB) at 96..224 MB; overlaps X1/F1/F2 which
    // are written only after attnv has consumed it (stream-ordered).
    bf16* SCb = (bf16*)(ws + 96 * MB);

    float* out_x  = (float*)d_out;
    float* scores = out_x + 4194304;

    F2BP fp;
    fp.src[0] = Wq; fp.dst[0] = WQb; fp.n4[0] = 262144;
    fp.src[1] = Wk; fp.dst[1] = WKb; fp.n4[1] = 262144;
    fp.src[2] = Wv; fp.dst[2] = WVb; fp.n4[2] = 262144;
    fp.src[3] = Wo; fp.dst[3] = WOb; fp.n4[3] = 262144;
    fp.src[4] = W1; fp.dst[4] = W1b; fp.n4[4] = 1048576;
    fp.src[5] = Wm; fp.dst[5] = WMb; fp.n4[5] = 4194304;
    fp.src[6] = W2; fp.dst[6] = W2b; fp.n4[6] = 1048576;
    hipLaunchKernelGGL(f2b_multi, dim3(1024, 7), dim3(256), 0, stream, fp);

    hipLaunchKernelGGL(ln_kernel, dim3(4096), dim3(256), 0, stream, x, g1, be1, HB);

    gemm128p<1024,1024,1024,1024,1><<<dim3(8,32,1), 512, 0, stream>>>(
        HB, WQb, nullptr, QB, bq, nullptr);
    gemm128p<1024,1024,1024,1024,1><<<dim3(8,32,1), 512, 0, stream>>>(
        HB, WKb, nullptr, KB, bk, nullptr);
    gemm128p<1024,1024,1024,4096,2><<<dim3(32,8,1), 512, 0, stream>>>(
        WVb, HB, nullptr, VT, bv, nullptr);

    // QK^T -> bf16 scores (K=64: stays on the short-K gemm_t)
    gemm_t<64,1024,1024,1024,1024,0,0,1><<<dim3(8,8,64), 256, 0, stream>>>(
        QB, KB, nullptr, SCb, nullptr, nullptr, 0.125f);

    hipLaunchKernelGGL(topk_softmax, dim3(16384), dim3(256), 0, stream,
                       (unsigned short*)SCb, scores);

    hipLaunchKernelGGL(attnv_kernel, dim3(1,8,64), dim3(256), 0, stream,
                       SCb, VT, AT);

    gemm128p<1024,1024,1024,1024,1><<<dim3(8,32,1), 512, 0, stream>>>(
        AT, WOb, X1, nullptr, bo, x);

    hipLaunchKernelGGL(ln_kernel, dim3(4096), dim3(256), 0, stream, X1, g2, be2, HB);

    gemm256<1024,1024,1024,4096><<<dim3(16,16,1), 512, 0, stream>>>(HB, W1b, F1, b1);
    gemm256<4096,4096,4096,4096><<<dim3(16,16,1), 512, 0, stream>>>(F1, WMb, F2, bm);

    gemm128p<4096,4096,4096,1024,1><<<dim3(8,32,1), 512, 0, stream>>>(
        F2, W2b, out_x, nullptr, b2, X1);
}

// Round 5
// 897.933 us; speedup vs baseline: 1.3594x; 1.0180x over previous
//
#include <hip/hip_runtime.h>
#include <hip/hip_bf16.h>

typedef __hip_bfloat16 bf16;
typedef float v4f __attribute__((ext_vector_type(4)));
typedef short v8s __attribute__((ext_vector_type(8)));

#define KSEL 307

__device__ static inline void async16(bf16* lds, const bf16* g) {
    __builtin_amdgcn_global_load_lds(
        (const __attribute__((address_space(1))) void*)g,
        (__attribute__((address_space(3))) void*)lds, 16, 0, 0);
}

__device__ static inline unsigned short f2bu(float f) {
    __hip_bfloat16 h = __float2bfloat16(f);
    return *reinterpret_cast<unsigned short*>(&h);
}

__device__ static inline unsigned pk2(float a, float b) {
    __hip_bfloat162 h = __float22bfloat162_rn(make_float2(a, b));
    return *reinterpret_cast<unsigned*>(&h);
}

// tanh-approx gelu via hardware exp: ~8 VALU ops vs ~35 for erff.
__device__ static inline float gelu_f(float v) {
    float c = v * fmaf(v * v, 0.0356774081f, 0.7978845608f);
    return v / (1.0f + __expf(-2.0f * c));
}

// ---------------- fp32 -> bf16 convert, 7 segments in one launch ----------------
struct F2BP { const float* src[7]; bf16* dst[7]; int n4[7]; };

__global__ void __launch_bounds__(256) f2b_multi(F2BP p) {
    int s = blockIdx.y;
    const float* __restrict__ in = p.src[s];
    bf16* __restrict__ out = p.dst[s];
    int n4 = p.n4[s];
    for (int i = blockIdx.x * 256 + threadIdx.x; i < n4; i += gridDim.x * 256) {
        float4 v = ((const float4*)in)[i];
        ushort4 u = make_ushort4(f2bu(v.x), f2bu(v.y), f2bu(v.z), f2bu(v.w));
        ((ushort4*)out)[i] = u;
    }
}

// ---------------- LayerNorm (row of 1024) ----------------
__global__ void __launch_bounds__(256) ln_kernel(const float* __restrict__ x,
                                                 const float* __restrict__ g,
                                                 const float* __restrict__ be,
                                                 bf16* __restrict__ out) {
    int row = blockIdx.x;
    int tid = threadIdx.x;
    const float* xr = x + row * 1024;
    float4 v = ((const float4*)xr)[tid];
    float s = v.x + v.y + v.z + v.w;
    float s2 = v.x*v.x + v.y*v.y + v.z*v.z + v.w*v.w;
    for (int off = 32; off > 0; off >>= 1) {
        s  += __shfl_down(s, off);
        s2 += __shfl_down(s2, off);
    }
    __shared__ float sh[4], sh2[4];
    int w = tid >> 6;
    if ((tid & 63) == 0) { sh[w] = s; sh2[w] = s2; }
    __syncthreads();
    float mean = (sh[0]+sh[1]+sh[2]+sh[3]) * (1.0f / 1024.f);
    float ms   = (sh2[0]+sh2[1]+sh2[2]+sh2[3]) * (1.0f / 1024.f);
    float var  = ms - mean*mean;
    float rs   = rsqrtf(var + 1e-5f);
    float4 gg = ((const float4*)g)[tid];
    float4 bb = ((const float4*)be)[tid];
    ushort4 o = make_ushort4(
        f2bu((v.x-mean)*rs*gg.x + bb.x),
        f2bu((v.y-mean)*rs*gg.y + bb.y),
        f2bu((v.z-mean)*rs*gg.z + bb.z),
        f2bu((v.w-mean)*rs*gg.w + bb.w));
    ((ushort4*)out)[row * 256 + tid] = o;
}

// ---------------- top-k threshold + masked softmax, ONE ROW PER WAVE ----------
// Ballot-bisection replaces the LDS radix histogram: finds the identical maximal
// 16-bit threshold t* = max{t : count(key >= t) >= KSEL} with zero LDS/atomics.
// (Normally-distributed scores concentrate in few radix bins -> the histogram
// atomics were heavily serialized; bisection is pure v_cmp + s_bcnt.)
__global__ void __launch_bounds__(256) topk_softmax(unsigned short* __restrict__ scb,
                                                    float* __restrict__ out) {
    const int tid = threadIdx.x;
    const int wid = tid >> 6, lane = tid & 63;
    const long long row = (long long)blockIdx.x * 4 + wid;
    unsigned short* pb = scb + row * 1024;
    float* po = out + row * 1024;

    unsigned key[16];
    float v[16];
#pragma unroll
    for (int j = 0; j < 4; ++j) {
        ushort4 t = *(const ushort4*)(pb + lane * 4 + j * 256);
        key[j*4+0] = t.x; key[j*4+1] = t.y; key[j*4+2] = t.z; key[j*4+3] = t.w;
    }
#pragma unroll
    for (int j = 0; j < 16; ++j) {
        unsigned u = key[j];
        v[j] = __uint_as_float(u << 16);            // exact bf16 -> f32
        key[j] = (u & 0x8000u) ? (0xFFFFu & ~u) : (u | 0x8000u);
    }

    // bisection on the 16-bit order-key space
    unsigned lo = 0, hi = 65536;
#pragma unroll
    for (int it = 0; it < 16; ++it) {
        unsigned mid = (lo + hi) >> 1;
        int cnt = 0;
#pragma unroll
        for (int j = 0; j < 16; ++j)
            cnt += (int)__popcll(__ballot(key[j] >= mid));
        if (cnt >= KSEL) lo = mid; else hi = mid;   // cnt is wave-uniform
    }
    const unsigned prefix = lo;

    // softmax over selected (key >= prefix); max is always selected
    float mx = v[0];
#pragma unroll
    for (int j = 1; j < 16; ++j) mx = fmaxf(mx, v[j]);
#pragma unroll
    for (int off = 32; off > 0; off >>= 1) mx = fmaxf(mx, __shfl_xor(mx, off));
    float sum = 0.f;
#pragma unroll
    for (int j = 0; j < 16; ++j) {
        bool sel = key[j] >= prefix;
        v[j] = sel ? __expf(v[j] - mx) : 0.f;
        sum += v[j];
    }
#pragma unroll
    for (int off = 32; off > 0; off >>= 1) sum += __shfl_xor(sum, off);
    float inv = 1.0f / sum;
#pragma unroll
    for (int j = 0; j < 4; ++j) {
        float4 o;
        o.x = v[j*4+0]*inv; o.y = v[j*4+1]*inv; o.z = v[j*4+2]*inv; o.w = v[j*4+3]*inv;
        *(float4*)(po + lane * 4 + j * 256) = o;
        uint2 u;                                    // bf16 copy for attnv
        u.x = pk2(o.x, o.y); u.y = pk2(o.z, o.w);
        *(uint2*)(pb + lane * 4 + j * 256) = u;
    }
}

// ---------------- QK^T (K=64): stage everything up front, one barrier, 32 MFMA.
// scores_bf16[z, tm..tm+128, tn..tn+128] = 0.125 * Q[b, :, h*64:+64] K^T
__global__ void __launch_bounds__(256) qk_kernel(const bf16* __restrict__ Q,
                                                 const bf16* __restrict__ Kb,
                                                 bf16* __restrict__ Cb) {
    __shared__ __align__(16) bf16 As[2][128 * 32];
    __shared__ __align__(16) bf16 Bs[2][128 * 32];
    const int z = blockIdx.z, b = z >> 4, h = z & 15;
    const int offA = b * 1048576 + h * 64;
    const int offC = z * 1048576;
    const int tid = threadIdx.x;
    const int w = tid >> 6, lane = tid & 63;
    const int tm = blockIdx.y * 128, tn = blockIdx.x * 128;
    const int q = lane >> 4, m16 = lane & 15;
    const int r0 = (w >> 1) * 64, c0 = (w & 1) * 64;
    const int srow = lane >> 2;
    const int scol = ((lane & 3) ^ ((lane >> 3) & 3)) * 8;
    const int sq = q ^ ((m16 >> 1) & 3);

    const bf16* Ab = Q  + offA + (tm + w * 16 + srow) * 1024 + scol;
    const bf16* Bb = Kb + offA + (tn + w * 16 + srow) * 1024 + scol;

    // stage both K-slabs of both operands (8 x 16B per lane)
#pragma unroll
    for (int s = 0; s < 2; ++s) {
        async16(&As[s][(w * 16) * 32],       Ab + s * 32);
        async16(&As[s][(64 + w * 16) * 32],  Ab + 64 * 1024 + s * 32);
        async16(&Bs[s][(w * 16) * 32],       Bb + s * 32);
        async16(&Bs[s][(64 + w * 16) * 32],  Bb + 64 * 1024 + s * 32);
    }
    __syncthreads();

    v4f acc[4][4];
#pragma unroll
    for (int i = 0; i < 4; ++i)
#pragma unroll
        for (int j = 0; j < 4; ++j) acc[i][j] = (v4f){0.f, 0.f, 0.f, 0.f};

#pragma unroll
    for (int s = 0; s < 2; ++s) {
        v8s af[4], bfr[4];
#pragma unroll
        for (int i = 0; i < 4; ++i)
            af[i] = *(const v8s*)&As[s][(r0 + 16 * i + m16) * 32 + sq * 8];
#pragma unroll
        for (int j = 0; j < 4; ++j)
            bfr[j] = *(const v8s*)&Bs[s][(c0 + 16 * j + m16) * 32 + sq * 8];
#pragma unroll
        for (int i = 0; i < 4; ++i)
#pragma unroll
            for (int j = 0; j < 4; ++j)
                acc[i][j] = __builtin_amdgcn_mfma_f32_16x16x32_bf16(af[i], bfr[j], acc[i][j], 0, 0, 0);
    }

#pragma unroll
    for (int i = 0; i < 4; ++i)
#pragma unroll
        for (int r = 0; r < 4; ++r) {
            int row = tm + r0 + 16 * i + q * 4 + r;
            int rowbase = offC + row * 1024 + tn + c0 + m16;
#pragma unroll
            for (int j = 0; j < 4; ++j)
                Cb[rowbase + 16 * j] = __float2bfloat16(acc[i][j][r] * 0.125f);
        }
}

// ---------------- gemm128p: 128x128, 8 waves (64x32 each), 4-deep LDS ring,
// counted vmcnt(2), ONE barrier per K-tile, T2 source-swizzle, XCD swizzle.
// Used for QKV, VT, Wo, W1, W2.
template<int K, int LDA, int LDB, int LDC, int BMODE, int ACT, int SWZ>
__global__ void __launch_bounds__(512, 2) gemm128p(const bf16* __restrict__ A,
                                                   const bf16* __restrict__ B,
                                                   float* __restrict__ Cf,
                                                   bf16* __restrict__ Cb,
                                                   const float* __restrict__ bias,
                                                   const float* __restrict__ resid) {
    __shared__ __align__(16) bf16 As[4][128 * 32];   // 4 ring slots, 64 KiB total
    __shared__ __align__(16) bf16 Bs[4][128 * 32];

    constexpr int nt = K / 32;
    static_assert(nt >= 4, "K >= 128");

    const int tid = threadIdx.x;
    const int w = tid >> 6, lane = tid & 63;
    const int wr = w >> 2, wc = w & 3;          // 2 x 4 wave grid: 64 x 32 per wave
    const int q = lane >> 4, m16 = lane & 15;

    int bx = blockIdx.x, by = blockIdx.y;
    if (SWZ) {   // bijective XCD-chunked remap (all grids are multiples of 8)
        int nx = gridDim.x;
        int bid = by * nx + bx;
        int nwg = nx * gridDim.y;
        int nb = (bid & 7) * (nwg >> 3) + (bid >> 3);
        bx = nb % nx; by = nb / nx;
    }
    const int tm = by * 128, tn = bx * 128;

    // staging: 512 threads cover 128 rows x 32 cols (16B/thread), source-swizzled
    const int srow = lane >> 2;
    const int scol = ((lane & 3) ^ ((lane >> 3) & 3)) * 8;
    const bf16* Ag = A + (tm + w * 16 + srow) * LDA + scol;
    const bf16* Bg = B + (tn + w * 16 + srow) * LDB + scol;

    v4f acc[4][2];
#pragma unroll
    for (int i = 0; i < 4; ++i)
#pragma unroll
        for (int j = 0; j < 2; ++j) acc[i][j] = (v4f){0.f, 0.f, 0.f, 0.f};

    const int sq = q ^ ((m16 >> 1) & 3);
    const int aoff = (wr * 64 + m16) * 32 + sq * 8;
    const int boff = (wc * 32 + m16) * 32 + sq * 8;

    // prologue: stage tiles 0,1 (2 loads/thread each)
#pragma unroll
    for (int t = 0; t < 2; ++t) {
        async16(&As[t][(w * 16) * 32], Ag + t * 32);
        async16(&Bs[t][(w * 16) * 32], Bg + t * 32);
    }
    asm volatile("s_waitcnt vmcnt(2)" ::: "memory");   // tile 0 landed
    __builtin_amdgcn_s_barrier();
    __builtin_amdgcn_sched_barrier(0);

#pragma unroll 1
    for (int t = 0; t < nt; ++t) {
        const int cur = t & 3, pre = (t + 2) & 3;
        const int kt = (t + 2 < nt) ? (t + 2) : 0;   // tail: dead staging
        v8s af[4], bfr[2];
#pragma unroll
        for (int i = 0; i < 4; ++i)
            af[i] = *(const v8s*)&As[cur][aoff + i * 512];
#pragma unroll
        for (int j = 0; j < 2; ++j)
            bfr[j] = *(const v8s*)&Bs[cur][boff + j * 512];
        async16(&As[pre][(w * 16) * 32], Ag + kt * 32);
        async16(&Bs[pre][(w * 16) * 32], Bg + kt * 32);
        asm volatile("s_waitcnt lgkmcnt(0)" ::: "memory");
        __builtin_amdgcn_sched_barrier(0);
        __builtin_amdgcn_s_setprio(1);
#pragma unroll
        for (int i = 0; i < 4; ++i)
#pragma unroll
            for (int j = 0; j < 2; ++j)
                acc[i][j] = __builtin_amdgcn_mfma_f32_16x16x32_bf16(af[i], bfr[j], acc[i][j], 0, 0, 0);
        __builtin_amdgcn_s_setprio(0);
        __builtin_amdgcn_sched_barrier(0);
        // tile t+1 landed (its 2 loads are oldest); t+2's stay in flight
        asm volatile("s_waitcnt vmcnt(2)" ::: "memory");
        __builtin_amdgcn_sched_barrier(0);
        __builtin_amdgcn_s_barrier();
        __builtin_amdgcn_sched_barrier(0);
    }
    asm volatile("s_waitcnt vmcnt(0)" ::: "memory");   // drain dead tail loads

    float bc[2];
#pragma unroll
    for (int j = 0; j < 2; ++j)
        bc[j] = (BMODE == 1) ? bias[tn + wc * 32 + 16 * j + m16] : 0.f;

#pragma unroll
    for (int i = 0; i < 4; ++i) {
#pragma unroll
        for (int r = 0; r < 4; ++r) {
            int row = tm + wr * 64 + 16 * i + q * 4 + r;
            float br = (BMODE == 2) ? bias[row] : 0.f;
            int rowbase = row * LDC + tn + wc * 32 + m16;
#pragma unroll
            for (int j = 0; j < 2; ++j) {
                float v = acc[i][j][r] + bc[j] + br;
                if (ACT) v = gelu_f(v);
                int idx = rowbase + 16 * j;
                if (resid) v += resid[idx];
                if (Cf) Cf[idx] = v;
                if (Cb) Cb[idx] = __float2bfloat16(v);
            }
        }
    }
}

// ---------------- 256x256 deep-pipelined GEMM (Wm): 8 waves, BK=32,
// 4-deep LDS ring, counted vmcnt(4), per-phase barrier+setprio interleave.
template<int K, int LDA, int LDB, int LDC>
__global__ void __launch_bounds__(512, 2) gemm256(const bf16* __restrict__ A,
                                                  const bf16* __restrict__ B,
                                                  bf16* __restrict__ C,
                                                  const float* __restrict__ bias) {
    __shared__ __align__(16) bf16 As[4][256 * 32];
    __shared__ __align__(16) bf16 Bs[4][256 * 32];

    constexpr int nt = K / 32;
    static_assert(nt >= 4 && (nt % 4) == 0, "K must be multiple of 128");

    const int tid = threadIdx.x;
    const int w = tid >> 6, lane = tid & 63;
    const int wm = w >> 2, wn = w & 3;
    const int q = lane >> 4, m16 = lane & 15;

    int bid = blockIdx.y * 16 + blockIdx.x;
    int xcd = bid & 7, inner = bid >> 3;
    int by = (xcd & 3) * 4 + (inner & 3);
    int bx = (xcd >> 2) * 8 + (inner >> 2);
    const int tm = by * 256, tn = bx * 256;

    const int srow = lane >> 2;
    const int scol = ((lane & 3) ^ ((lane >> 3) & 3)) * 8;
    const bf16* Ag = A + (tm + w * 32 + srow) * LDA + scol;
    const bf16* Bg = B + (tn + w * 32 + srow) * LDB + scol;

    v4f acc[8][4];
#pragma unroll
    for (int i = 0; i < 8; ++i)
#pragma unroll
        for (int j = 0; j < 4; ++j) acc[i][j] = (v4f){0.f, 0.f, 0.f, 0.f};

    const int sq = q ^ ((m16 >> 1) & 3);
    const int aoff = (wm * 128 + m16) * 32 + sq * 8;
    const int boff = (wn * 64 + m16) * 32 + sq * 8;

#pragma unroll
    for (int t = 0; t < 2; ++t) {
        async16(&As[t][(w * 32) * 32],      Ag + t * 32);
        async16(&As[t][(w * 32 + 16) * 32], Ag + 16 * LDA + t * 32);
        async16(&Bs[t][(w * 32) * 32],      Bg + t * 32);
        async16(&Bs[t][(w * 32 + 16) * 32], Bg + 16 * LDB + t * 32);
    }
    asm volatile("s_waitcnt vmcnt(4)" ::: "memory");
    __builtin_amdgcn_s_barrier();
    __builtin_amdgcn_sched_barrier(0);

#pragma unroll 1
    for (int t4 = 0; t4 < nt; t4 += 4) {
#pragma unroll
        for (int tt = 0; tt < 4; ++tt) {
            const int t = t4 + tt;
            const int cur = tt;
            const int pre = (tt + 2) & 3;
            int kt = t + 2; if (kt >= nt) kt = 0;
            const bf16* Asrc = Ag + kt * 32;
            const bf16* Bsrc = Bg + kt * 32;

            v8s af[4], bfr[4];
#pragma unroll
            for (int i = 0; i < 4; ++i)
                af[i] = *(const v8s*)&As[cur][aoff + i * 512];
#pragma unroll
            for (int j = 0; j < 4; ++j)
                bfr[j] = *(const v8s*)&Bs[cur][boff + j * 512];
            async16(&As[pre][(w * 32) * 32],      Asrc);
            async16(&As[pre][(w * 32 + 16) * 32], Asrc + 16 * LDA);
            __builtin_amdgcn_s_barrier();
            asm volatile("s_waitcnt lgkmcnt(0)" ::: "memory");
            __builtin_amdgcn_sched_barrier(0);
            __builtin_amdgcn_s_setprio(1);
#pragma unroll
            for (int i = 0; i < 4; ++i)
#pragma unroll
                for (int j = 0; j < 4; ++j)
                    acc[i][j] = __builtin_amdgcn_mfma_f32_16x16x32_bf16(af[i], bfr[j], acc[i][j], 0, 0, 0);
            __builtin_amdgcn_s_setprio(0);
            __builtin_amdgcn_sched_barrier(0);
            __builtin_amdgcn_s_barrier();
            __builtin_amdgcn_sched_barrier(0);

            v8s af2[4];
#pragma unroll
            for (int i = 0; i < 4; ++i)
                af2[i] = *(const v8s*)&As[cur][aoff + 2048 + i * 512];
            async16(&Bs[pre][(w * 32) * 32],      Bsrc);
            async16(&Bs[pre][(w * 32 + 16) * 32], Bsrc + 16 * LDB);
            __builtin_amdgcn_s_barrier();
            asm volatile("s_waitcnt lgkmcnt(0)" ::: "memory");
            __builtin_amdgcn_sched_barrier(0);
            __builtin_amdgcn_s_setprio(1);
#pragma unroll
            for (int i = 0; i < 4; ++i)
#pragma unroll
                for (int j = 0; j < 4; ++j)
                    acc[i + 4][j] = __builtin_amdgcn_mfma_f32_16x16x32_bf16(af2[i], bfr[j], acc[i + 4][j], 0, 0, 0);
            __builtin_amdgcn_s_setprio(0);
            asm volatile("s_waitcnt vmcnt(4)" ::: "memory");
            __builtin_amdgcn_sched_barrier(0);
            __builtin_amdgcn_s_barrier();
            __builtin_amdgcn_sched_barrier(0);
        }
    }

    float bc[4];
#pragma unroll
    for (int j = 0; j < 4; ++j)
        bc[j] = bias[tn + wn * 64 + 16 * j + m16];

#pragma unroll
    for (int i = 0; i < 8; ++i) {
#pragma unroll
        for (int r = 0; r < 4; ++r) {
            int row = tm + wm * 128 + 16 * i + q * 4 + r;
            int rowbase = row * LDC + tn + wn * 64 + m16;
#pragma unroll
            for (int j = 0; j < 4; ++j) {
                float v = acc[i][j][r] + bc[j];
                v = gelu_f(v);
                C[rowbase + 16 * j] = __float2bfloat16(v);
            }
        }
    }
}

// ---------------- attnV (bf16 P): out[b,s,h*64+c] = sum_k P[z,s,k] * VT[h*64+c,b*1024+k]
__global__ void __launch_bounds__(256) attnv_kernel(const bf16* __restrict__ P,
                                                    const bf16* __restrict__ VT,
                                                    bf16* __restrict__ out) {
    __shared__ __align__(16) bf16 As[4][128 * 32];
    __shared__ __align__(16) bf16 Bs[4][64 * 32];
    int z = blockIdx.z, b = z >> 4, h = z & 15;
    int tid = threadIdx.x, w = tid >> 6, lane = tid & 63;
    int q = lane >> 4, m16 = lane & 15;
    int srow = lane >> 2;
    int scol = ((lane & 3) ^ ((lane >> 3) & 3)) * 8;
    const int sq = q ^ ((m16 >> 1) & 3);

    const bf16* Ab = P + z * 1048576 + (blockIdx.y * 128 + w * 16 + srow) * 1024 + scol;
    const bf16* Bb = VT + (h * 64 + w * 16 + srow) * 4096 + b * 1024 + scol;

    v4f acc[2][4];
#pragma unroll
    for (int i = 0; i < 2; ++i)
#pragma unroll
        for (int j = 0; j < 4; ++j) acc[i][j] = (v4f){0.f, 0.f, 0.f, 0.f};

    const int aoff = (w * 32 + m16) * 32 + sq * 8;
    const int boff = (m16) * 32 + sq * 8;

#pragma unroll
    for (int t = 0; t < 2; ++t) {
        async16(&As[t][(w * 16) * 32],        Ab + t * 32);
        async16(&As[t][(64 + w * 16) * 32],   Ab + 64 * 1024 + t * 32);
        async16(&Bs[t][(w * 16) * 32],        Bb + t * 32);
    }
    asm volatile("s_waitcnt vmcnt(3)" ::: "memory");
    __builtin_amdgcn_s_barrier();
    __builtin_amdgcn_sched_barrier(0);

#pragma unroll 1
    for (int t = 0; t < 32; ++t) {
        const int cur = t & 3, pre = (t + 2) & 3;
        const int kt = (t + 2 < 32) ? (t + 2) : 0;
        v8s af[2], bfr[4];
        af[0] = *(const v8s*)&As[cur][aoff];
        af[1] = *(const v8s*)&As[cur][aoff + 512];
#pragma unroll
        for (int j = 0; j < 4; ++j)
            bfr[j] = *(const v8s*)&Bs[cur][boff + j * 512];
        async16(&As[pre][(w * 16) * 32],      Ab + kt * 32);
        async16(&As[pre][(64 + w * 16) * 32], Ab + 64 * 1024 + kt * 32);
        async16(&Bs[pre][(w * 16) * 32],      Bb + kt * 32);
        asm volatile("s_waitcnt lgkmcnt(0)" ::: "memory");
        __builtin_amdgcn_sched_barrier(0);
        __builtin_amdgcn_s_setprio(1);
#pragma unroll
        for (int i = 0; i < 2; ++i)
#pragma unroll
            for (int j = 0; j < 4; ++j)
                acc[i][j] = __builtin_amdgcn_mfma_f32_16x16x32_bf16(af[i], bfr[j], acc[i][j], 0, 0, 0);
        __builtin_amdgcn_s_setprio(0);
        __builtin_amdgcn_sched_barrier(0);
        asm volatile("s_waitcnt vmcnt(3)" ::: "memory");
        __builtin_amdgcn_sched_barrier(0);
        __builtin_amdgcn_s_barrier();
        __builtin_amdgcn_sched_barrier(0);
    }
    asm volatile("s_waitcnt vmcnt(0)" ::: "memory");

    int orow0 = b * 1024 + blockIdx.y * 128 + w * 32;
#pragma unroll
    for (int i = 0; i < 2; ++i)
#pragma unroll
        for (int r = 0; r < 4; ++r) {
            int row = orow0 + 16 * i + q * 4 + r;
#pragma unroll
            for (int j = 0; j < 4; ++j) {
                int col = h * 64 + 16 * j + m16;
                out[row * 1024 + col] = __float2bfloat16(acc[i][j][r]);
            }
        }
}

// ---------------- host ----------------
extern "C" void kernel_launch(void* const* d_in, const int* in_sizes, int n_in,
                              void* d_out, int out_size, void* d_ws, size_t ws_size,
                              hipStream_t stream) {
    (void)in_sizes; (void)n_in; (void)out_size; (void)ws_size;
    const float* x  = (const float*)d_in[0];
    const float* Wq = (const float*)d_in[1];
    const float* bq = (const float*)d_in[2];
    const float* Wk = (const float*)d_in[3];
    const float* bk = (const float*)d_in[4];
    const float* Wv = (const float*)d_in[5];
    const float* bv = (const float*)d_in[6];
    const float* Wo = (const float*)d_in[7];
    const float* bo = (const float*)d_in[8];
    const float* W1 = (const float*)d_in[9];
    const float* b1 = (const float*)d_in[10];
    const float* Wm = (const float*)d_in[11];
    const float* bm = (const float*)d_in[12];
    const float* W2 = (const float*)d_in[13];
    const float* b2 = (const float*)d_in[14];
    const float* g1 = (const float*)d_in[15];
    const float* be1 = (const float*)d_in[16];
    const float* g2 = (const float*)d_in[17];
    const float* be2 = (const float*)d_in[18];

    char* ws = (char*)d_ws;
    const size_t MB = 1024 * 1024;
    bf16* WQb = (bf16*)(ws + 0 * MB);
    bf16* WKb = (bf16*)(ws + 2 * MB);
    bf16* WVb = (bf16*)(ws + 4 * MB);
    bf16* WOb = (bf16*)(ws + 6 * MB);
    bf16* W1b = (bf16*)(ws + 8 * MB);
    bf16* WMb = (bf16*)(ws + 16 * MB);
    bf16* W2b = (bf16*)(ws + 48 * MB);
    bf16* HB  = (bf16*)(ws + 56 * MB);
    bf16* QB  = (bf16*)(ws + 64 * MB);
    bf16* KB  = (bf16*)(ws + 72 * MB);
    bf16* VT  = (bf16*)(ws + 80 * MB);
    bf16* AT  = (bf16*)(ws + 88 * MB);
    float* X1 = (float*)(ws + 96 * MB);
    bf16* F1  = (bf16*)(ws + 112 * MB);
    bf16* F2  = (bf16*)(ws + 144 * MB);
    // bf16 scores/probs scratch (128 MB) at 96..224 MB; overlaps X1/F1/F2 which
    // are written only after attnv has consumed it (stream-ordered).
    bf16* SCb = (bf16*)(ws + 96 * MB);

    float* out_x  = (float*)d_out;
    float* scores = out_x + 4194304;

    F2BP fp;
    fp.src[0] = Wq; fp.dst[0] = WQb; fp.n4[0] = 262144;
    fp.src[1] = Wk; fp.dst[1] = WKb; fp.n4[1] = 262144;
    fp.src[2] = Wv; fp.dst[2] = WVb; fp.n4[2] = 262144;
    fp.src[3] = Wo; fp.dst[3] = WOb; fp.n4[3] = 262144;
    fp.src[4] = W1; fp.dst[4] = W1b; fp.n4[4] = 1048576;
    fp.src[5] = Wm; fp.dst[5] = WMb; fp.n4[5] = 4194304;
    fp.src[6] = W2; fp.dst[6] = W2b; fp.n4[6] = 1048576;
    hipLaunchKernelGGL(f2b_multi, dim3(1024, 7), dim3(256), 0, stream, fp);

    hipLaunchKernelGGL(ln_kernel, dim3(4096), dim3(256), 0, stream, x, g1, be1, HB);

    gemm128p<1024,1024,1024,1024,1,0,1><<<dim3(8,32,1), 512, 0, stream>>>(
        HB, WQb, nullptr, QB, bq, nullptr);
    gemm128p<1024,1024,1024,1024,1,0,1><<<dim3(8,32,1), 512, 0, stream>>>(
        HB, WKb, nullptr, KB, bk, nullptr);
    gemm128p<1024,1024,1024,4096,2,0,1><<<dim3(32,8,1), 512, 0, stream>>>(
        WVb, HB, nullptr, VT, bv, nullptr);

    // QK^T -> bf16 scores
    hipLaunchKernelGGL(qk_kernel, dim3(8,8,64), dim3(256), 0, stream, QB, KB, SCb);

    hipLaunchKernelGGL(topk_softmax, dim3(16384), dim3(256), 0, stream,
                       (unsigned short*)SCb, scores);

    hipLaunchKernelGGL(attnv_kernel, dim3(1,8,64), dim3(256), 0, stream,
                       SCb, VT, AT);

    gemm128p<1024,1024,1024,1024,1,0,1><<<dim3(8,32,1), 512, 0, stream>>>(
        AT, WOb, X1, nullptr, bo, x);

    hipLaunchKernelGGL(ln_kernel, dim3(4096), dim3(256), 0, stream, X1, g2, be2, HB);

    // FFN
    gemm128p<1024,1024,1024,4096,1,1,1><<<dim3(32,32,1), 512, 0, stream>>>(
        HB, W1b, nullptr, F1, b1, nullptr);
    gemm256<4096,4096,4096,4096><<<dim3(16,16,1), 512, 0, stream>>>(F1, WMb, F2, bm);

    gemm128p<4096,4096,4096,1024,1,0,1><<<dim3(8,32,1), 512, 0, stream>>>(
        F2, W2b, out_x, nullptr, b2, X1);
}